// Round 8
// baseline (2053.949 us; speedup 1.0000x reference)
//
#include <hip/hip_runtime.h>
#include <hip/hip_bf16.h>
#include <math.h>

#define T_TOK 16384
#define H_DIM 1024
#define E_NUM 64
#define I_DIM 768
#define TOPK  8
#define NGRP  8
#define KGRP  4
#define S_ASN (T_TOK*TOPK)        /* 131072 assignments */
#define BM 128
#define BK 64
#define MAXBLK (S_ASN/BM + E_NUM) /* fallback-path bound */
#define NCB1 6                    /* ffn1: 128-col chunks of I */
#define NCB2 4                    /* ffn2: 128-col chunks per 512-col half */
#define JS1 1024                  /* ffn1 per-XCD block slots */
#define JS2 768                   /* ffn2 per-XCD block slots */

typedef __attribute__((ext_vector_type(4))) float f4v;
typedef __attribute__((ext_vector_type(8))) short s8v;
typedef __attribute__((ext_vector_type(4))) unsigned short u4sv;

#define GLDS16(g, l) __builtin_amdgcn_global_load_lds( \
    (const __attribute__((address_space(1))) void*)(g), \
    (__attribute__((address_space(3))) void*)(l), 16, 0, 0)

static __device__ __forceinline__ short f2bf(float f){
  union { float f; unsigned u; } a; a.f = f;
  unsigned u = a.u;
  unsigned r = (u + 0x7fffu + ((u >> 16) & 1u)) >> 16;  /* RNE */
  return (short)r;
}
static __device__ __forceinline__ float bf2f(unsigned short h){
  union { unsigned u; float f; } a; a.u = ((unsigned)h) << 16; return a.f;
}
static __device__ __forceinline__ s8v cvt8(f4v a, f4v b){
  s8v r;
  r[0]=f2bf(a[0]); r[1]=f2bf(a[1]); r[2]=f2bf(a[2]); r[3]=f2bf(a[3]);
  r[4]=f2bf(b[0]); r[5]=f2bf(b[1]); r[6]=f2bf(b[2]); r[7]=f2bf(b[3]);
  return r;
}

/* ---------------- fp32 -> bf16 bulk cast ----------------------------------- */
__launch_bounds__(256)
__global__ void cast_kernel(const float* __restrict__ src,
                            short* __restrict__ dst, long n8)
{
  long i = (long)blockIdx.x*blockDim.x + threadIdx.x;
  long stride = (long)gridDim.x*blockDim.x;
  for (; i < n8; i += stride){
    f4v a = *(const f4v*)(src + i*8);
    f4v b = *(const f4v*)(src + i*8 + 4);
    *(s8v*)(dst + i*8) = cvt8(a, b);
  }
}

/* ---------------- gate logits + hidden bf16 side-output -------------------- */
__launch_bounds__(256)
__global__ void gate_kernel(const float* __restrict__ hidden,
                            const float* __restrict__ gate_w,
                            double* __restrict__ logits,
                            short*  __restrict__ hb)   /* may be null */
{
  __shared__ float sX[64][33];
  __shared__ float sW[64][33];
  const int tid  = threadIdx.x;
  const int t0   = blockIdx.x * 64;
  const int srow = tid >> 2;
  const int scol = (tid & 3) * 8;
  const int tx = tid & 15, ty = tid >> 4;
  double acc[4][4];
  #pragma unroll
  for (int i=0;i<4;i++)
    #pragma unroll
    for (int j=0;j<4;j++) acc[i][j]=0.0;

  for (int k0=0;k0<H_DIM;k0+=32){
    f4v a0 = *(const f4v*)&hidden[(size_t)(t0+srow)*H_DIM + k0 + scol];
    f4v a1 = *(const f4v*)&hidden[(size_t)(t0+srow)*H_DIM + k0 + scol + 4];
    f4v b0 = *(const f4v*)&gate_w[(size_t)srow*H_DIM + k0 + scol];
    f4v b1 = *(const f4v*)&gate_w[(size_t)srow*H_DIM + k0 + scol + 4];
    if (hb)  /* bf16 side-output: each element written exactly once */
      *(s8v*)&hb[(size_t)(t0+srow)*H_DIM + k0 + scol] = cvt8(a0, a1);
    __syncthreads();
    #pragma unroll
    for (int j=0;j<4;j++){
      sX[srow][scol+j]   = a0[j];  sX[srow][scol+4+j] = a1[j];
      sW[srow][scol+j]   = b0[j];  sW[srow][scol+4+j] = b1[j];
    }
    __syncthreads();
    #pragma unroll
    for (int kk=0;kk<32;kk++){
      float xv[4], wv[4];
      #pragma unroll
      for (int i=0;i<4;i++){ xv[i]=sX[ty*4+i][kk]; wv[i]=sW[tx*4+i][kk]; }
      #pragma unroll
      for (int i=0;i<4;i++)
        #pragma unroll
        for (int j=0;j<4;j++)
          acc[i][j] += (double)xv[i] * (double)wv[j];
    }
  }
  #pragma unroll
  for (int i=0;i<4;i++)
    #pragma unroll
    for (int j=0;j<4;j++)
      logits[(size_t)(t0+ty*4+i)*E_NUM + tx*4+j] = acc[i][j];
}

/* ---------------- routing: grouped top-k in fp64 --------------------------- */
__global__ void route_kernel(const double* __restrict__ logits,
                             const float*  __restrict__ bias,
                             int*   __restrict__ topk_idx,
                             float* __restrict__ topk_w,
                             int*   __restrict__ counts)
{
  const int t = blockIdx.x * blockDim.x + threadIdx.x;
  if (t >= T_TOK) return;
  const double* lg = logits + (size_t)t * E_NUM;
  double sc[E_NUM], sch[E_NUM];
  for (int e2=0;e2<E_NUM;e2++){
    double s = 1.0 / (1.0 + exp(-lg[e2]));
    sc[e2]  = s;
    sch[e2] = s + (double)bias[e2];
  }
  double gs[NGRP];
  for (int g=0;g<NGRP;g++){
    double m1=-1e300, m2=-1e300;
    for (int j=0;j<8;j++){
      double v = sch[g*8+j];
      if (v > m1){ m2 = m1; m1 = v; } else if (v > m2){ m2 = v; }
    }
    gs[g] = m1 + m2;
  }
  unsigned gsel = 0;
  for (int r=0;r<KGRP;r++){
    int best = 0; double bv = -1.0e308;
    for (int g=0;g<NGRP;g++)
      if (!((gsel>>g)&1u) && gs[g] > bv){ bv = gs[g]; best = g; }
    gsel |= 1u << best;
  }
  unsigned long long used = 0ULL;
  double wsum = 0.0;
  int sel[TOPK]; double w[TOPK];
  for (int r=0;r<TOPK;r++){
    int best = 0; double bv = -1.0e308;
    for (int e2=0;e2<E_NUM;e2++){
      if ((used>>e2)&1ULL) continue;
      if (!((gsel>>(e2>>3))&1u)) continue;
      if (sch[e2] > bv){ bv = sch[e2]; best = e2; }
    }
    used |= 1ULL << best;
    sel[r] = best;
    w[r]   = sc[best];
    wsum  += w[r];
  }
  double inv = 1.0 / (wsum + 1e-20);
  for (int r=0;r<TOPK;r++){
    topk_idx[(size_t)t*TOPK + r] = sel[r];
    topk_w  [(size_t)t*TOPK + r] = (float)(w[r]*inv);
    atomicAdd(&counts[sel[r]], 1);
  }
}

/* ---------------- prefix sums + per-XCD queue geometry --------------------- */
__global__ void scan_kernel(const int* __restrict__ counts,
                            int* __restrict__ offsets,
                            int* __restrict__ blk_start,
                            int* __restrict__ xoff,
                            int* __restrict__ qblk)
{
  if (threadIdx.x == 0 && blockIdx.x == 0){
    int off = 0, blk = 0;
    int cnt[8];
    for (int x=0;x<8;x++) cnt[x]=0;
    for (int e=0;e<E_NUM;e++){
      offsets[e] = off; blk_start[e] = blk;
      int nblk = (counts[e] + BM - 1) / BM;
      xoff[e] = cnt[e & 7];
      cnt[e & 7] += nblk;
      off += counts[e];
      blk += nblk;
    }
    offsets[E_NUM] = off; blk_start[E_NUM] = blk;
    for (int x=0;x<8;x++) qblk[x] = cnt[x];
  }
}

/* ---------------- scatter token lists + inverse positions ------------------ */
__global__ void scatter_kernel(const int* __restrict__ topk_idx,
                               const float* __restrict__ topk_w,
                               const int* __restrict__ offsets,
                               int* __restrict__ cursor,
                               int* __restrict__ token_list,
                               float* __restrict__ weight_list,
                               int* __restrict__ pos_list)
{
  const int t = blockIdx.x*blockDim.x + threadIdx.x;
  if (t >= T_TOK) return;
  for (int r=0;r<TOPK;r++){
    int   e2 = topk_idx[(size_t)t*TOPK + r];
    float wv = topk_w [(size_t)t*TOPK + r];
    int p = atomicAdd(&cursor[e2], 1);
    token_list [offsets[e2] + p] = t;
    weight_list[offsets[e2] + p] = wv;
    pos_list[(size_t)t*TOPK + r] = offsets[e2] + p;
  }
}

/* ======================= FAST PATH (bf16 + global_load_lds) ================ */
/* LDS written LINEARLY by global_load_lds; XOR swizzle lives in the per-lane
   GLOBAL source address (inverse) and in the ds_read (forward):
   LDS slot (row, sl) holds global 16B-slot (sl ^ (row&7)).
   XCD binding: expert e -> XCD e%8 (blockIdx round-robins XCDs); within an
   XCD, work is cb-major / rb-fastest, so consecutive same-XCD blocks share
   one (e,cb) weight panel -> panel fetched into ONE private L2, once.       */

/* ffn1: h = silu(X Wg^T) * (X Wu^T) * w.
   512 thr / 8 waves, BM=128, BN=128, BK=64. Wave-tile 64x32 (x2 for g,u). */
__launch_bounds__(512, 4)
__global__ void ffn1_fast(const short* __restrict__ hid_bf,
                          const short* __restrict__ wg_bf,
                          const short* __restrict__ wu_bf,
                          const int*   __restrict__ token_list,
                          const float* __restrict__ weight_list,
                          const int*   __restrict__ offsets,
                          const int*   __restrict__ xoff,
                          const int*   __restrict__ qblk,
                          short*       __restrict__ h_all)
{
  __shared__ short lsX[128*64];
  __shared__ short lsG[128*64];
  __shared__ short lsU[128*64];
  __shared__ float lsWt[128];

  const int xcd = blockIdx.x & 7;
  const int j0  = blockIdx.x >> 3;
  const int qn  = qblk[xcd] * NCB1;

  const int tid = threadIdx.x;
  const int lane = tid & 63, wid = tid >> 6;   /* 8 waves */
  const int wm = wid >> 2, wn = wid & 3;       /* 2 x 4 wave grid */
  const int l15 = lane & 15, l4 = lane >> 4;

  for (int j = j0; j < qn; j += JS1){
    /* decompose j -> (e, cb, rb): experts xcd, xcd+8, ..., xcd+56 */
    int e = -1, nb = 0;
    #pragma unroll
    for (int i=0;i<8;i++){
      int ee  = xcd + (i<<3);
      int nbe = (offsets[ee+1] - offsets[ee] + BM-1) >> 7;
      int hi  = (xoff[ee] + nbe) * NCB1;
      if (e < 0 && j < hi){ e = ee; nb = nbe; }
    }
    const int local = j - xoff[e]*NCB1;
    const int cb = local / nb;
    const int rb = local - cb*nb;
    const int base = offsets[e];
    const int n_e  = offsets[e+1] - base;
    const int row0 = rb * BM;

    __syncthreads();   /* previous item's LDS use fully done */
    if (tid < BM) lsWt[tid] = ((row0+tid) < n_e) ? weight_list[base+row0+tid] : 0.f;

    const short* srcA[2];
    #pragma unroll
    for (int i=0;i<2;i++){
      int s_lin = i*512 + tid;
      int row = s_lin >> 3, sl = s_lin & 7;
      int asn = base + row0 + row; if (asn >= S_ASN) asn = S_ASN-1;
      int tok = token_list[asn];
      srcA[i] = hid_bf + (size_t)tok*H_DIM + ((sl ^ (row&7))<<3);
    }
    const short* srcG[2]; const short* srcU[2];
    #pragma unroll
    for (int i=0;i<2;i++){
      int s_lin = i*512 + tid;
      int row = s_lin >> 3, sl = s_lin & 7;
      size_t wrow = ((size_t)e*I_DIM + cb*128 + row)*H_DIM + ((sl ^ (row&7))<<3);
      srcG[i] = wg_bf + wrow;
      srcU[i] = wu_bf + wrow;
    }
    short* dstA0 = lsX + wid*512;
    short* dstG0 = lsG + wid*512;
    short* dstU0 = lsU + wid*512;

    f4v accg[4][2], accu[4][2];
    #pragma unroll
    for (int m=0;m<4;m++)
      #pragma unroll
      for (int n=0;n<2;n++){
        accg[m][n]=(f4v){0.f,0.f,0.f,0.f};
        accu[m][n]=(f4v){0.f,0.f,0.f,0.f};
      }

    for (int k0=0; k0<H_DIM; k0+=BK){
      __syncthreads();
      #pragma unroll
      for (int i=0;i<2;i++) GLDS16(srcA[i]+k0, dstA0 + i*4096);
      #pragma unroll
      for (int i=0;i<2;i++) GLDS16(srcG[i]+k0, dstG0 + i*4096);
      #pragma unroll
      for (int i=0;i<2;i++) GLDS16(srcU[i]+k0, dstU0 + i*4096);
      __syncthreads();
      #pragma unroll
      for (int kk=0;kk<2;kk++){
        s8v af[4], bg[2], bu[2];
        #pragma unroll
        for (int m=0;m<4;m++){
          int r = wm*64 + m*16 + l15;
          int s = (kk*4 + l4) ^ (r & 7);
          af[m] = *(const s8v*)&lsX[r*64 + (s<<3)];
        }
        #pragma unroll
        for (int n=0;n<2;n++){
          int r = wn*32 + n*16 + l15;
          int s = (kk*4 + l4) ^ (r & 7);
          bg[n] = *(const s8v*)&lsG[r*64 + (s<<3)];
          bu[n] = *(const s8v*)&lsU[r*64 + (s<<3)];
        }
        #pragma unroll
        for (int m=0;m<4;m++)
          #pragma unroll
          for (int n=0;n<2;n++){
            accg[m][n] = __builtin_amdgcn_mfma_f32_16x16x32_bf16(af[m], bg[n], accg[m][n], 0,0,0);
            accu[m][n] = __builtin_amdgcn_mfma_f32_16x16x32_bf16(af[m], bu[n], accu[m][n], 0,0,0);
          }
      }
    }
    #pragma unroll
    for (int m=0;m<4;m++){
      #pragma unroll
      for (int i=0;i<4;i++){
        int r = wm*64 + m*16 + l4*4 + i;
        if (row0 + r < n_e){
          float wgt = lsWt[r];
          size_t hb = (size_t)(base+row0+r)*I_DIM + (size_t)cb*128;
          #pragma unroll
          for (int n=0;n<2;n++){
            int c = wn*32 + n*16 + l15;
            float g = accg[m][n][i], u = accu[m][n][i];
            float s = g / (1.f + __expf(-g));
            h_all[hb + c] = f2bf(s * u * wgt);
          }
        }
      }
    }
  }
}

/* ffn2y: y[asn, half-cols] = h_all @ Wd^T  (dense bf16 writes, NO atomics).
   Round-4 verified GEMM config: 256 thr / 4 waves (2x2), BM=128, BN=128,
   BK=64, wave-tile 64x64, acc[4][4].  Same XCD binding / cb-major order. */
__launch_bounds__(256, 3)
__global__ void ffn2y_fast(const short* __restrict__ h_all,
                           const short* __restrict__ wd_bf,
                           const int*   __restrict__ offsets,
                           const int*   __restrict__ xoff,
                           const int*   __restrict__ qblk,
                           short*       __restrict__ y,     /* [S_ASN][512] */
                           int          cb0)                /* half: 0 or 1 */
{
  __shared__ short lsA[128*64];
  __shared__ short lsB[128*64];

  const int xcd = blockIdx.x & 7;
  const int j0  = blockIdx.x >> 3;
  const int qn  = qblk[xcd] * NCB2;

  const int tid = threadIdx.x;
  const int lane = tid & 63, wid = tid >> 6;
  const int wm = wid >> 1, wn = wid & 1;     /* 2 x 2 wave grid */
  const int l15 = lane & 15, l4 = lane >> 4;

  for (int j = j0; j < qn; j += JS2){
    int e = -1, nb = 0;
    #pragma unroll
    for (int i=0;i<8;i++){
      int ee  = xcd + (i<<3);
      int nbe = (offsets[ee+1] - offsets[ee] + BM-1) >> 7;
      int hi  = (xoff[ee] + nbe) * NCB2;
      if (e < 0 && j < hi){ e = ee; nb = nbe; }
    }
    const int local = j - xoff[e]*NCB2;
    const int cby = local / nb;              /* 0..3 within the half */
    const int rb  = local - cby*nb;
    const int cbg = cb0*4 + cby;             /* global 128-col chunk of H */
    const int base = offsets[e];
    const int n_e  = offsets[e+1] - base;
    const int row0 = rb * BM;

    __syncthreads();

    const short* srcA[4]; const short* srcB[4];
    #pragma unroll
    for (int i=0;i<4;i++){
      int s_lin = i*256 + tid;
      int row = s_lin >> 3, sl = s_lin & 7;
      int arow = base + row0 + row; if (arow >= S_ASN) arow = S_ASN-1;
      srcA[i] = h_all + (size_t)arow*I_DIM + ((sl ^ (row&7))<<3);
      srcB[i] = wd_bf + ((size_t)e*H_DIM + cbg*128 + row)*I_DIM + ((sl ^ (row&7))<<3);
    }
    short* dstA0 = lsA + wid*512;
    short* dstB0 = lsB + wid*512;

    f4v acc[4][4];
    #pragma unroll
    for (int m=0;m<4;m++)
      #pragma unroll
      for (int n=0;n<4;n++) acc[m][n]=(f4v){0.f,0.f,0.f,0.f};

    for (int k0=0; k0<I_DIM; k0+=BK){
      __syncthreads();
      #pragma unroll
      for (int i=0;i<4;i++) GLDS16(srcA[i]+k0, dstA0 + i*2048);
      #pragma unroll
      for (int i=0;i<4;i++) GLDS16(srcB[i]+k0, dstB0 + i*2048);
      __syncthreads();
      #pragma unroll
      for (int kk=0;kk<2;kk++){
        s8v af[4], bf[4];
        #pragma unroll
        for (int m=0;m<4;m++){
          int r = wm*64 + m*16 + l15;
          int s = (kk*4 + l4) ^ (r & 7);
          af[m] = *(const s8v*)&lsA[r*64 + (s<<3)];
        }
        #pragma unroll
        for (int n=0;n<4;n++){
          int r = wn*64 + n*16 + l15;
          int s = (kk*4 + l4) ^ (r & 7);
          bf[n] = *(const s8v*)&lsB[r*64 + (s<<3)];
        }
        #pragma unroll
        for (int m=0;m<4;m++)
          #pragma unroll
          for (int n=0;n<4;n++)
            acc[m][n] = __builtin_amdgcn_mfma_f32_16x16x32_bf16(af[m], bf[n], acc[m][n], 0,0,0);
      }
    }
    #pragma unroll
    for (int m=0;m<4;m++){
      #pragma unroll
      for (int i=0;i<4;i++){
        int r = wm*64 + m*16 + l4*4 + i;
        if (row0 + r < n_e){
          size_t yb = (size_t)(base+row0+r)*512 + (size_t)cby*128;
          #pragma unroll
          for (int n=0;n<4;n++){
            int c = wn*64 + n*16 + l15;
            y[yb + c] = f2bf(acc[m][n][i]);
          }
        }
      }
    }
  }
}

/* combine: out[t, half-cols] = sum_r y[pos[t,r], :]  (fixed r order) */
__launch_bounds__(256)
__global__ void combine_kernel(const short* __restrict__ y,
                               const int*   __restrict__ pos,
                               float*       __restrict__ out,
                               int cb0)
{
  const int tid = threadIdx.x;
  const int t = blockIdx.x*2 + (tid >> 7);
  const int c = (tid & 127) * 4;
  const int* pp = pos + (size_t)t*TOPK;
  float s0=0.f, s1=0.f, s2=0.f, s3=0.f;
  #pragma unroll
  for (int r=0;r<TOPK;r++){
    int row = pp[r];
    u4sv v = *(const u4sv*)&y[(size_t)row*512 + c];
    s0 += bf2f(v[0]); s1 += bf2f(v[1]); s2 += bf2f(v[2]); s3 += bf2f(v[3]);
  }
  f4v o = {s0,s1,s2,s3};
  *(f4v*)&out[(size_t)t*H_DIM + (size_t)cb0*512 + c] = o;
}

/* ======================= SLOW FALLBACK (round-1, fp32 reg-staged) ========== */
__launch_bounds__(512, 2)
__global__ void ffn1_kernel(const float* __restrict__ hidden,
                            const float* __restrict__ w_gate,
                            const float* __restrict__ w_up,
                            const int*   __restrict__ token_list,
                            const float* __restrict__ weight_list,
                            const int*   __restrict__ offsets,
                            const int*   __restrict__ blk_start,
                            short*       __restrict__ h_all)
{
  __shared__ short lsX[BM*64];
  __shared__ short lsG[BM*64];
  __shared__ short lsU[BM*64];
  __shared__ float lsWt[BM];

  const int bx = blockIdx.x;
  if (bx >= blk_start[E_NUM]) return;
  int e = 0;
  while (blk_start[e+1] <= bx) ++e;
  const int rb   = bx - blk_start[e];
  const int cb   = blockIdx.y;
  const int base = offsets[e];
  const int n_e  = offsets[e+1] - base;
  const int row0 = rb * BM;

  const int tid   = threadIdx.x;
  const int srow  = tid >> 2;
  const int scol  = (tid & 3) << 4;
  const int slot0 = (tid & 3) << 1;
  const int wsl0  = srow*64 + (((slot0  ) ^ (srow & 7)) << 3);
  const int wsl1  = srow*64 + (((slot0+1) ^ (srow & 7)) << 3);

  const bool tvalid = (row0 + srow) < n_e;
  int tok = 0;
  if (tvalid) tok = token_list[base + row0 + srow];
  const float* xsrc = hidden + (size_t)tok * H_DIM + scol;
  const size_t woff = (size_t)e * I_DIM * H_DIM + (size_t)(cb*128 + srow) * H_DIM + scol;
  const float* gsrc = w_gate + woff;
  const float* usrc = w_up   + woff;

  const int lane = tid & 63, wid = tid >> 6;
  const int wm = wid >> 2, wn = wid & 3;
  const int l15 = lane & 15, l4 = lane >> 4;

  f4v accg[4][2], accu[4][2];
  #pragma unroll
  for (int m=0;m<4;m++)
    #pragma unroll
    for (int n=0;n<2;n++){
      accg[m][n]=(f4v){0.f,0.f,0.f,0.f};
      accu[m][n]=(f4v){0.f,0.f,0.f,0.f};
    }

  for (int k0=0; k0<H_DIM; k0+=BK){
    f4v x0,x1,x2,x3;
    if (tvalid){
      x0 = *(const f4v*)(xsrc+k0);   x1 = *(const f4v*)(xsrc+k0+4);
      x2 = *(const f4v*)(xsrc+k0+8); x3 = *(const f4v*)(xsrc+k0+12);
    } else {
      x0=x1=x2=x3=(f4v){0.f,0.f,0.f,0.f};
    }
    f4v g0 = *(const f4v*)(gsrc+k0),   g1 = *(const f4v*)(gsrc+k0+4);
    f4v g2 = *(const f4v*)(gsrc+k0+8), g3 = *(const f4v*)(gsrc+k0+12);
    f4v u0 = *(const f4v*)(usrc+k0),   u1 = *(const f4v*)(usrc+k0+4);
    f4v u2 = *(const f4v*)(usrc+k0+8), u3 = *(const f4v*)(usrc+k0+12);
    __syncthreads();
    *(s8v*)&lsX[wsl0] = cvt8(x0,x1);  *(s8v*)&lsX[wsl1] = cvt8(x2,x3);
    *(s8v*)&lsG[wsl0] = cvt8(g0,g1);  *(s8v*)&lsG[wsl1] = cvt8(g2,g3);
    *(s8v*)&lsU[wsl0] = cvt8(u0,u1);  *(s8v*)&lsU[wsl1] = cvt8(u2,u3);
    __syncthreads();
    #pragma unroll
    for (int kk=0;kk<2;kk++){
      s8v af[4], bg[2], bu[2];
      #pragma unroll
      for (int m=0;m<4;m++){
        int r = wm*64 + m*16 + l15;
        int s = (kk*4 + l4) ^ (r & 7);
        af[m] = *(const s8v*)&lsX[r*64 + (s<<3)];
      }
      #pragma unroll
      for (int n=0;n<2;n++){
        int r = wn*32 + n*16 + l15;
        int s = (kk*4 + l4) ^ (r & 7);
        bg[n] = *(const s8v*)&lsG[r*64 + (s<<3)];
        bu[n] = *(const s8v*)&lsU[r*64 + (s<<3)];
      }
      #pragma unroll
      for (int m=0;m<4;m++)
        #pragma unroll
        for (int n=0;n<2;n++){
          accg[m][n] = __builtin_amdgcn_mfma_f32_16x16x32_bf16(af[m], bg[n], accg[m][n], 0,0,0);
          accu[m][n] = __builtin_amdgcn_mfma_f32_16x16x32_bf16(af[m], bu[n], accu[m][n], 0,0,0);
        }
    }
  }
  if (tid < BM) lsWt[tid] = ((row0+tid) < n_e) ? weight_list[base+row0+tid] : 0.f;
  __syncthreads();
  #pragma unroll
  for (int m=0;m<4;m++){
    #pragma unroll
    for (int i=0;i<4;i++){
      int r = wm*64 + m*16 + l4*4 + i;
      if (row0 + r < n_e){
        float wgt = lsWt[r];
        size_t hb = (size_t)(base+row0+r)*I_DIM + (size_t)cb*128;
        #pragma unroll
        for (int n=0;n<2;n++){
          int c = wn*32 + n*16 + l15;
          float g = accg[m][n][i], u = accu[m][n][i];
          float s = g / (1.f + __expf(-g));
          h_all[hb + c] = f2bf(s * u * wgt);
        }
      }
    }
  }
}

__launch_bounds__(512, 2)
__global__ void ffn2_kernel(const short* __restrict__ h_all,
                            const float* __restrict__ w_down,
                            const int*   __restrict__ token_list,
                            const int*   __restrict__ offsets,
                            const int*   __restrict__ blk_start,
                            float*       __restrict__ out)
{
  __shared__ short lsA[BM*64];
  __shared__ short lsB[BM*64];
  __shared__ int   lsT[BM];

  const int bx = blockIdx.x;
  if (bx >= blk_start[E_NUM]) return;
  int e = 0;
  while (blk_start[e+1] <= bx) ++e;
  const int rb   = bx - blk_start[e];
  const int cb   = blockIdx.y;
  const int base = offsets[e];
  const int n_e  = offsets[e+1] - base;
  const int row0 = rb * BM;

  const int tid   = threadIdx.x;
  const int srow  = tid >> 2;
  const int slot0 = (tid & 3) << 1;
  const int wsl0  = srow*64 + (((slot0  ) ^ (srow & 7)) << 3);
  const int wsl1  = srow*64 + (((slot0+1) ^ (srow & 7)) << 3);

  int arow = base + row0 + srow;
  if (arow >= S_ASN) arow = S_ASN - 1;
  const short* asrc = h_all + (size_t)arow*I_DIM + ((tid&3)<<4);
  const float* bsrc = w_down + (size_t)e*H_DIM*I_DIM
                    + (size_t)(cb*128 + srow)*I_DIM + ((tid&3)<<4);

  const int lane = tid & 63, wid = tid >> 6;
  const int wm = wid >> 2, wn = wid & 3;
  const int l15 = lane & 15, l4 = lane >> 4;

  f4v acc[4][2];
  #pragma unroll
  for (int m=0;m<4;m++)
    #pragma unroll
    for (int n=0;n<2;n++) acc[m][n]=(f4v){0.f,0.f,0.f,0.f};

  for (int k0=0; k0<I_DIM; k0+=BK){
    s8v alo = *(const s8v*)(asrc + k0);
    s8v ahi = *(const s8v*)(asrc + k0 + 8);
    f4v b0 = *(const f4v*)(bsrc+k0),   b1 = *(const f4v*)(bsrc+k0+4);
    f4v b2 = *(const f4v*)(bsrc+k0+8), b3 = *(const f4v*)(bsrc+k0+12);
    __syncthreads();
    *(s8v*)&lsA[wsl0] = alo;          *(s8v*)&lsA[wsl1] = ahi;
    *(s8v*)&lsB[wsl0] = cvt8(b0,b1);  *(s8v*)&lsB[wsl1] = cvt8(b2,b3);
    __syncthreads();
    #pragma unroll
    for (int kk=0;kk<2;kk++){
      s8v af[4], bf[2];
      #pragma unroll
      for (int m=0;m<4;m++){
        int r = wm*64 + m*16 + l15;
        int s = (kk*4 + l4) ^ (r & 7);
        af[m] = *(const s8v*)&lsA[r*64 + (s<<3)];
      }
      #pragma unroll
      for (int n=0;n<2;n++){
        int r = wn*32 + n*16 + l15;
        int s = (kk*4 + l4) ^ (r & 7);
        bf[n] = *(const s8v*)&lsB[r*64 + (s<<3)];
      }
      #pragma unroll
      for (int m=0;m<4;m++)
        #pragma unroll
        for (int n=0;n<2;n++)
          acc[m][n] = __builtin_amdgcn_mfma_f32_16x16x32_bf16(af[m], bf[n], acc[m][n], 0,0,0);
    }
  }
  if (tid < BM) lsT[tid] = ((row0+tid) < n_e) ? token_list[base+row0+tid] : -1;
  __syncthreads();
  #pragma unroll
  for (int m=0;m<4;m++){
    #pragma unroll
    for (int i=0;i<4;i++){
      int r = wm*64 + m*16 + l4*4 + i;
      int tk = lsT[r];
      if (tk >= 0){
        #pragma unroll
        for (int n=0;n<2;n++){
          int c = cb*128 + wn*32 + n*16 + l15;
          atomicAdd(&out[(size_t)tk*H_DIM + c], acc[m][n][i]);
        }
      }
    }
  }
}

/* ---------------- launch --------------------------------------------------- */
extern "C" void kernel_launch(void* const* d_in, const int* in_sizes, int n_in,
                              void* d_out, int out_size, void* d_ws, size_t ws_size,
                              hipStream_t stream)
{
  const float* hidden = (const float*)d_in[0];
  const float* gate_w = (const float*)d_in[1];
  const float* bias   = (const float*)d_in[2];
  const float* w_gate = (const float*)d_in[3];
  const float* w_up   = (const float*)d_in[4];
  const float* w_down = (const float*)d_in[5];
  float* out = (float*)d_out;

  char* ws = (char*)d_ws;
  size_t off = 0;
  #define WALLOC(bytes) (ws + off); off += (((size_t)(bytes)) + 255) & ~(size_t)255
  double* logits    = (double*)WALLOC((size_t)T_TOK*E_NUM*8);
  int*    topk_idx  = (int*)   WALLOC((size_t)T_TOK*TOPK*4);
  float*  topk_w    = (float*) WALLOC((size_t)T_TOK*TOPK*4);
  int*    counts    = (int*)   WALLOC(256);
  int*    cursor    = (int*)   WALLOC(256);
  int*    offsets   = (int*)   WALLOC(512);
  int*    blk_st    = (int*)   WALLOC(512);
  int*    xoff      = (int*)   WALLOC(256);
  int*    qblk      = (int*)   WALLOC(256);
  int*    token_l   = (int*)   WALLOC((size_t)S_ASN*4);
  float*  weight_l  = (float*) WALLOC((size_t)S_ASN*4);
  int*    pos_l     = (int*)   WALLOC((size_t)S_ASN*4);
  short*  h_all     = (short*) WALLOC((size_t)S_ASN*I_DIM*2);
  const size_t base_need = off;
  short*  hid_bf    = (short*) WALLOC((size_t)T_TOK*H_DIM*2);      /* 33.55 MB */
  short*  wg_bf     = (short*) WALLOC((size_t)E_NUM*I_DIM*H_DIM*2);/* 100.66 MB */
  short*  wu_bf     = (short*) WALLOC((size_t)E_NUM*I_DIM*H_DIM*2);
  short*  wd_bf     = (short*) WALLOC((size_t)E_NUM*H_DIM*I_DIM*2);
  const size_t fast_need = off;
  #undef WALLOC
  /* y (S_ASN*512*2 = 134,217,728 B) aliases hid_bf+wg_bf (33,554,432 +
     100,663,296 = 134,217,728 B exactly) — both dead once ffn1 completes. */
  short* y_all = hid_bf;

  const bool fast = (ws_size >= fast_need);
  if (ws_size < base_need) return;

  hipMemsetAsync(counts, 0, 512, stream);                 /* counts + cursor */

  gate_kernel   <<<T_TOK/64,  256, 0, stream>>>(hidden, gate_w, logits,
                                                fast ? hid_bf : (short*)0);
  route_kernel  <<<T_TOK/256, 256, 0, stream>>>(logits, bias, topk_idx, topk_w, counts);
  scan_kernel   <<<1, 64, 0, stream>>>(counts, offsets, blk_st, xoff, qblk);
  scatter_kernel<<<T_TOK/256, 256, 0, stream>>>(topk_idx, topk_w, offsets, cursor,
                                                token_l, weight_l, pos_l);
  if (fast){
    long n8w = (long)E_NUM*I_DIM*H_DIM/8;   /* 6,291,456 = 3072*256*8 exactly */
    cast_kernel<<<3072, 256, 0, stream>>>(w_gate, wg_bf, n8w);
    cast_kernel<<<3072, 256, 0, stream>>>(w_up,   wu_bf, n8w);
    cast_kernel<<<3072, 256, 0, stream>>>(w_down, wd_bf, n8w);
    ffn1_fast<<<8*JS1, 512, 0, stream>>>(hid_bf, wg_bf, wu_bf, token_l, weight_l,
                                         offsets, xoff, qblk, h_all);
    for (int half = 0; half < 2; ++half){
      ffn2y_fast<<<8*JS2, 256, 0, stream>>>(h_all, wd_bf, offsets, xoff, qblk,
                                            y_all, half);
      combine_kernel<<<T_TOK/2, 256, 0, stream>>>(y_all, pos_l, out, half);
    }
  } else {
    hipMemsetAsync(out, 0, (size_t)T_TOK*H_DIM*4, stream);
    dim3 g1(MAXBLK, I_DIM/128);
    ffn1_kernel<<<g1, 512, 0, stream>>>(hidden, w_gate, w_up, token_l, weight_l,
                                        offsets, blk_st, h_all);
    dim3 g2(MAXBLK, H_DIM/128);
    ffn2_kernel<<<g2, 512, 0, stream>>>(h_all, w_down, token_l, offsets, blk_st, out);
  }
}

// Round 9
// 1697.054 us; speedup vs baseline: 1.2103x; 1.2103x over previous
//
#include <hip/hip_runtime.h>
#include <hip/hip_bf16.h>
#include <math.h>

#define T_TOK 16384
#define H_DIM 1024
#define E_NUM 64
#define I_DIM 768
#define TOPK  8
#define NGRP  8
#define KGRP  4
#define S_ASN (T_TOK*TOPK)        /* 131072 assignments */
#define BM 128
#define BK 64
#define MAXBLK (S_ASN/BM + E_NUM) /* 1088: upper bound of sum(ceil(n_e/BM)) */

typedef __attribute__((ext_vector_type(4))) float f4v;
typedef __attribute__((ext_vector_type(8))) short s8v;
typedef __attribute__((ext_vector_type(4))) unsigned short u4sv;

#define GLDS16(g, l) __builtin_amdgcn_global_load_lds( \
    (const __attribute__((address_space(1))) void*)(g), \
    (__attribute__((address_space(3))) void*)(l), 16, 0, 0)

static __device__ __forceinline__ short f2bf(float f){
  union { float f; unsigned u; } a; a.f = f;
  unsigned u = a.u;
  unsigned r = (u + 0x7fffu + ((u >> 16) & 1u)) >> 16;  /* RNE */
  return (short)r;
}
static __device__ __forceinline__ float bf2f(unsigned short h){
  union { unsigned u; float f; } a; a.u = ((unsigned)h) << 16; return a.f;
}
static __device__ __forceinline__ s8v cvt8(f4v a, f4v b){
  s8v r;
  r[0]=f2bf(a[0]); r[1]=f2bf(a[1]); r[2]=f2bf(a[2]); r[3]=f2bf(a[3]);
  r[4]=f2bf(b[0]); r[5]=f2bf(b[1]); r[6]=f2bf(b[2]); r[7]=f2bf(b[3]);
  return r;
}

/* ---------------- fp32 -> bf16 bulk cast (non-temporal streaming) ---------- */
__launch_bounds__(256)
__global__ void cast_kernel(const float* __restrict__ src,
                            short* __restrict__ dst, long n8)
{
  long i = (long)blockIdx.x*blockDim.x + threadIdx.x;
  long stride = (long)gridDim.x*blockDim.x;
  for (; i < n8; i += stride){
    f4v a = __builtin_nontemporal_load((const f4v*)(src + i*8));
    f4v b = __builtin_nontemporal_load((const f4v*)(src + i*8 + 4));
    __builtin_nontemporal_store(cvt8(a, b), (s8v*)(dst + i*8));
  }
}

/* ---------------- gate logits + hidden bf16 side-output -------------------- */
__launch_bounds__(256)
__global__ void gate_kernel(const float* __restrict__ hidden,
                            const float* __restrict__ gate_w,
                            double* __restrict__ logits,
                            short*  __restrict__ hb)   /* may be null */
{
  __shared__ float sX[64][33];
  __shared__ float sW[64][33];
  const int tid  = threadIdx.x;
  const int t0   = blockIdx.x * 64;
  const int srow = tid >> 2;
  const int scol = (tid & 3) * 8;
  const int tx = tid & 15, ty = tid >> 4;
  double acc[4][4];
  #pragma unroll
  for (int i=0;i<4;i++)
    #pragma unroll
    for (int j=0;j<4;j++) acc[i][j]=0.0;

  for (int k0=0;k0<H_DIM;k0+=32){
    f4v a0 = *(const f4v*)&hidden[(size_t)(t0+srow)*H_DIM + k0 + scol];
    f4v a1 = *(const f4v*)&hidden[(size_t)(t0+srow)*H_DIM + k0 + scol + 4];
    f4v b0 = *(const f4v*)&gate_w[(size_t)srow*H_DIM + k0 + scol];
    f4v b1 = *(const f4v*)&gate_w[(size_t)srow*H_DIM + k0 + scol + 4];
    if (hb)  /* bf16 side-output: each element written exactly once */
      *(s8v*)&hb[(size_t)(t0+srow)*H_DIM + k0 + scol] = cvt8(a0, a1);
    __syncthreads();
    #pragma unroll
    for (int j=0;j<4;j++){
      sX[srow][scol+j]   = a0[j];  sX[srow][scol+4+j] = a1[j];
      sW[srow][scol+j]   = b0[j];  sW[srow][scol+4+j] = b1[j];
    }
    __syncthreads();
    #pragma unroll
    for (int kk=0;kk<32;kk++){
      float xv[4], wv[4];
      #pragma unroll
      for (int i=0;i<4;i++){ xv[i]=sX[ty*4+i][kk]; wv[i]=sW[tx*4+i][kk]; }
      #pragma unroll
      for (int i=0;i<4;i++)
        #pragma unroll
        for (int j=0;j<4;j++)
          acc[i][j] += (double)xv[i] * (double)wv[j];
    }
  }
  #pragma unroll
  for (int i=0;i<4;i++)
    #pragma unroll
    for (int j=0;j<4;j++)
      logits[(size_t)(t0+ty*4+i)*E_NUM + tx*4+j] = acc[i][j];
}

/* ---------------- routing: grouped top-k in fp64 --------------------------- */
__global__ void route_kernel(const double* __restrict__ logits,
                             const float*  __restrict__ bias,
                             int*   __restrict__ topk_idx,
                             float* __restrict__ topk_w,
                             int*   __restrict__ counts)
{
  const int t = blockIdx.x * blockDim.x + threadIdx.x;
  if (t >= T_TOK) return;
  const double* lg = logits + (size_t)t * E_NUM;
  double sc[E_NUM], sch[E_NUM];
  for (int e2=0;e2<E_NUM;e2++){
    double s = 1.0 / (1.0 + exp(-lg[e2]));
    sc[e2]  = s;
    sch[e2] = s + (double)bias[e2];
  }
  double gs[NGRP];
  for (int g=0;g<NGRP;g++){
    double m1=-1e300, m2=-1e300;
    for (int j=0;j<8;j++){
      double v = sch[g*8+j];
      if (v > m1){ m2 = m1; m1 = v; } else if (v > m2){ m2 = v; }
    }
    gs[g] = m1 + m2;
  }
  unsigned gsel = 0;
  for (int r=0;r<KGRP;r++){
    int best = 0; double bv = -1.0e308;
    for (int g=0;g<NGRP;g++)
      if (!((gsel>>g)&1u) && gs[g] > bv){ bv = gs[g]; best = g; }
    gsel |= 1u << best;
  }
  unsigned long long used = 0ULL;
  double wsum = 0.0;
  int sel[TOPK]; double w[TOPK];
  for (int r=0;r<TOPK;r++){
    int best = 0; double bv = -1.0e308;
    for (int e2=0;e2<E_NUM;e2++){
      if ((used>>e2)&1ULL) continue;
      if (!((gsel>>(e2>>3))&1u)) continue;
      if (sch[e2] > bv){ bv = sch[e2]; best = e2; }
    }
    used |= 1ULL << best;
    sel[r] = best;
    w[r]   = sc[best];
    wsum  += w[r];
  }
  double inv = 1.0 / (wsum + 1e-20);
  for (int r=0;r<TOPK;r++){
    topk_idx[(size_t)t*TOPK + r] = sel[r];
    topk_w  [(size_t)t*TOPK + r] = (float)(w[r]*inv);
    atomicAdd(&counts[sel[r]], 1);
  }
}

/* ---------------- prefix sums --------------------------------------------- */
__global__ void scan_kernel(const int* __restrict__ counts,
                            int* __restrict__ offsets,
                            int* __restrict__ blk_start)
{
  if (threadIdx.x == 0 && blockIdx.x == 0){
    int off = 0, blk = 0;
    for (int e=0;e<E_NUM;e++){
      offsets[e] = off; blk_start[e] = blk;
      off += counts[e];
      blk += (counts[e] + BM - 1) / BM;
    }
    offsets[E_NUM] = off; blk_start[E_NUM] = blk;
  }
}

/* ---------------- scatter token lists + inverse positions ------------------ */
__global__ void scatter_kernel(const int* __restrict__ topk_idx,
                               const float* __restrict__ topk_w,
                               const int* __restrict__ offsets,
                               int* __restrict__ cursor,
                               int* __restrict__ token_list,
                               float* __restrict__ weight_list,
                               int* __restrict__ pos_list)
{
  const int t = blockIdx.x*blockDim.x + threadIdx.x;
  if (t >= T_TOK) return;
  for (int r=0;r<TOPK;r++){
    int   e2 = topk_idx[(size_t)t*TOPK + r];
    float wv = topk_w [(size_t)t*TOPK + r];
    int p = atomicAdd(&cursor[e2], 1);
    token_list [offsets[e2] + p] = t;
    weight_list[offsets[e2] + p] = wv;
    pos_list[(size_t)t*TOPK + r] = offsets[e2] + p;
  }
}

/* ======================= FAST PATH (bf16 + global_load_lds) ================ */
/* LDS written LINEARLY by global_load_lds; XOR swizzle lives in the per-lane
   GLOBAL source address (inverse) and in the ds_read (forward):
   LDS slot (row, sl) holds global 16B-slot (sl ^ (row&7)).                   */

/* ffn1: h = silu(X Wg^T) * (X Wu^T) * w.
   512 thr / 8 waves, BM=128, BN=128, BK=64. Wave-tile 64x32 (x2 for g,u). */
__launch_bounds__(512, 4)
__global__ void ffn1_fast(const short* __restrict__ hid_bf,
                          const short* __restrict__ wg_bf,
                          const short* __restrict__ wu_bf,
                          const int*   __restrict__ token_list,
                          const float* __restrict__ weight_list,
                          const int*   __restrict__ offsets,
                          const int*   __restrict__ blk_start,
                          short*       __restrict__ h_all)
{
  __shared__ short lsX[128*64];
  __shared__ short lsG[128*64];
  __shared__ short lsU[128*64];
  __shared__ float lsWt[128];

  const int bx = blockIdx.x;
  if (bx >= blk_start[E_NUM]) return;
  int e = 0;
  while (blk_start[e+1] <= bx) ++e;
  const int rb   = bx - blk_start[e];
  const int cb   = blockIdx.y;               /* 0..5 : 128-col chunk of I */
  const int base = offsets[e];
  const int n_e  = offsets[e+1] - base;
  const int row0 = rb * BM;

  const int tid = threadIdx.x;
  const int lane = tid & 63, wid = tid >> 6;   /* 8 waves */
  const int wm = wid >> 2, wn = wid & 3;       /* 2 x 4 wave grid */
  const int l15 = lane & 15, l4 = lane >> 4;

  if (tid < BM) lsWt[tid] = ((row0+tid) < n_e) ? weight_list[base+row0+tid] : 0.f;

  const short* srcA[2];
  #pragma unroll
  for (int i=0;i<2;i++){
    int s_lin = i*512 + tid;
    int row = s_lin >> 3, sl = s_lin & 7;
    int asn = base + row0 + row; if (asn >= S_ASN) asn = S_ASN-1;
    int tok = token_list[asn];
    srcA[i] = hid_bf + (size_t)tok*H_DIM + ((sl ^ (row&7))<<3);
  }
  const short* srcG[2]; const short* srcU[2];
  #pragma unroll
  for (int i=0;i<2;i++){
    int s_lin = i*512 + tid;
    int row = s_lin >> 3, sl = s_lin & 7;
    size_t wrow = ((size_t)e*I_DIM + cb*128 + row)*H_DIM + ((sl ^ (row&7))<<3);
    srcG[i] = wg_bf + wrow;
    srcU[i] = wu_bf + wrow;
  }
  short* dstA0 = lsX + wid*512;
  short* dstG0 = lsG + wid*512;
  short* dstU0 = lsU + wid*512;

  f4v accg[4][2], accu[4][2];
  #pragma unroll
  for (int m=0;m<4;m++)
    #pragma unroll
    for (int n=0;n<2;n++){
      accg[m][n]=(f4v){0.f,0.f,0.f,0.f};
      accu[m][n]=(f4v){0.f,0.f,0.f,0.f};
    }

  for (int k0=0; k0<H_DIM; k0+=BK){
    __syncthreads();
    #pragma unroll
    for (int i=0;i<2;i++) GLDS16(srcA[i]+k0, dstA0 + i*4096);
    #pragma unroll
    for (int i=0;i<2;i++) GLDS16(srcG[i]+k0, dstG0 + i*4096);
    #pragma unroll
    for (int i=0;i<2;i++) GLDS16(srcU[i]+k0, dstU0 + i*4096);
    __syncthreads();
    #pragma unroll
    for (int kk=0;kk<2;kk++){
      s8v af[4], bg[2], bu[2];
      #pragma unroll
      for (int m=0;m<4;m++){
        int r = wm*64 + m*16 + l15;
        int s = (kk*4 + l4) ^ (r & 7);
        af[m] = *(const s8v*)&lsX[r*64 + (s<<3)];
      }
      #pragma unroll
      for (int n=0;n<2;n++){
        int r = wn*32 + n*16 + l15;
        int s = (kk*4 + l4) ^ (r & 7);
        bg[n] = *(const s8v*)&lsG[r*64 + (s<<3)];
        bu[n] = *(const s8v*)&lsU[r*64 + (s<<3)];
      }
      #pragma unroll
      for (int m=0;m<4;m++)
        #pragma unroll
        for (int n=0;n<2;n++){
          accg[m][n] = __builtin_amdgcn_mfma_f32_16x16x32_bf16(af[m], bg[n], accg[m][n], 0,0,0);
          accu[m][n] = __builtin_amdgcn_mfma_f32_16x16x32_bf16(af[m], bu[n], accu[m][n], 0,0,0);
        }
    }
  }
  #pragma unroll
  for (int m=0;m<4;m++){
    #pragma unroll
    for (int i=0;i<4;i++){
      int r = wm*64 + m*16 + l4*4 + i;
      if (row0 + r < n_e){
        float wgt = lsWt[r];
        size_t hb = (size_t)(base+row0+r)*I_DIM + (size_t)cb*128;
        #pragma unroll
        for (int n=0;n<2;n++){
          int c = wn*32 + n*16 + l15;
          float g = accg[m][n][i], u = accu[m][n][i];
          float s = g / (1.f + __expf(-g));
          h_all[hb + c] = f2bf(s * u * wgt);
        }
      }
    }
  }
}

/* ffn2y: y[asn, half-cols] = h_all @ Wd^T  (dense bf16 writes, NO atomics).
   Round-4 verified GEMM config: 256 thr / 4 waves (2x2), BM=128, BN=128,
   BK=64, wave-tile 64x64, acc[4][4], VGPR=76 measured.  cby = 0..3 selects
   the 128-col chunk within the 512-col half.                                */
__launch_bounds__(256, 3)
__global__ void ffn2y_fast(const short* __restrict__ h_all,
                           const short* __restrict__ wd_bf,
                           const int*   __restrict__ offsets,
                           const int*   __restrict__ blk_start,
                           short*       __restrict__ y,     /* [S_ASN][512] */
                           int          cb0)                /* half: 0 or 1 */
{
  __shared__ short lsA[128*64];
  __shared__ short lsB[128*64];

  const int bx = blockIdx.x;
  if (bx >= blk_start[E_NUM]) return;
  int e = 0;
  while (blk_start[e+1] <= bx) ++e;
  const int rb   = bx - blk_start[e];
  const int cby  = blockIdx.y;               /* 0..3 within the half */
  const int cbg  = cb0*4 + cby;              /* global 128-col chunk of H */
  const int base = offsets[e];
  const int n_e  = offsets[e+1] - base;
  const int row0 = rb * BM;

  const int tid = threadIdx.x;
  const int lane = tid & 63, wid = tid >> 6;
  const int wm = wid >> 1, wn = wid & 1;     /* 2 x 2 wave grid */
  const int l15 = lane & 15, l4 = lane >> 4;

  const short* srcA[4]; const short* srcB[4];
  #pragma unroll
  for (int i=0;i<4;i++){
    int s_lin = i*256 + tid;
    int row = s_lin >> 3, sl = s_lin & 7;
    int arow = base + row0 + row; if (arow >= S_ASN) arow = S_ASN-1;
    srcA[i] = h_all + (size_t)arow*I_DIM + ((sl ^ (row&7))<<3);
    srcB[i] = wd_bf + ((size_t)e*H_DIM + cbg*128 + row)*I_DIM + ((sl ^ (row&7))<<3);
  }
  short* dstA0 = lsA + wid*512;
  short* dstB0 = lsB + wid*512;

  f4v acc[4][4];
  #pragma unroll
  for (int m=0;m<4;m++)
    #pragma unroll
    for (int n=0;n<4;n++) acc[m][n]=(f4v){0.f,0.f,0.f,0.f};

  for (int k0=0; k0<I_DIM; k0+=BK){
    __syncthreads();
    #pragma unroll
    for (int i=0;i<4;i++) GLDS16(srcA[i]+k0, dstA0 + i*2048);
    #pragma unroll
    for (int i=0;i<4;i++) GLDS16(srcB[i]+k0, dstB0 + i*2048);
    __syncthreads();
    #pragma unroll
    for (int kk=0;kk<2;kk++){
      s8v af[4], bf[4];
      #pragma unroll
      for (int m=0;m<4;m++){
        int r = wm*64 + m*16 + l15;
        int s = (kk*4 + l4) ^ (r & 7);
        af[m] = *(const s8v*)&lsA[r*64 + (s<<3)];
      }
      #pragma unroll
      for (int n=0;n<4;n++){
        int r = wn*64 + n*16 + l15;
        int s = (kk*4 + l4) ^ (r & 7);
        bf[n] = *(const s8v*)&lsB[r*64 + (s<<3)];
      }
      #pragma unroll
      for (int m=0;m<4;m++)
        #pragma unroll
        for (int n=0;n<4;n++)
          acc[m][n] = __builtin_amdgcn_mfma_f32_16x16x32_bf16(af[m], bf[n], acc[m][n], 0,0,0);
    }
  }
  #pragma unroll
  for (int m=0;m<4;m++){
    #pragma unroll
    for (int i=0;i<4;i++){
      int r = wm*64 + m*16 + l4*4 + i;
      if (row0 + r < n_e){
        size_t yb = (size_t)(base+row0+r)*512 + (size_t)cby*128;
        #pragma unroll
        for (int n=0;n<4;n++){
          int c = wn*64 + n*16 + l15;
          y[yb + c] = f2bf(acc[m][n][i]);
        }
      }
    }
  }
}

/* combine: out[t, half-cols] = sum_r y[pos[t,r], :]  (fixed r order) */
__launch_bounds__(256)
__global__ void combine_kernel(const short* __restrict__ y,
                               const int*   __restrict__ pos,
                               float*       __restrict__ out,
                               int cb0)
{
  const int tid = threadIdx.x;
  const int t = blockIdx.x*2 + (tid >> 7);
  const int c = (tid & 127) * 4;
  const int* pp = pos + (size_t)t*TOPK;
  float s0=0.f, s1=0.f, s2=0.f, s3=0.f;
  #pragma unroll
  for (int r=0;r<TOPK;r++){
    int row = pp[r];
    u4sv v = *(const u4sv*)&y[(size_t)row*512 + c];
    s0 += bf2f(v[0]); s1 += bf2f(v[1]); s2 += bf2f(v[2]); s3 += bf2f(v[3]);
  }
  f4v o = {s0,s1,s2,s3};
  *(f4v*)&out[(size_t)t*H_DIM + (size_t)cb0*512 + c] = o;
}

/* ======================= SLOW FALLBACK (round-1, fp32 reg-staged) ========== */
__launch_bounds__(512, 2)
__global__ void ffn1_kernel(const float* __restrict__ hidden,
                            const float* __restrict__ w_gate,
                            const float* __restrict__ w_up,
                            const int*   __restrict__ token_list,
                            const float* __restrict__ weight_list,
                            const int*   __restrict__ offsets,
                            const int*   __restrict__ blk_start,
                            short*       __restrict__ h_all)
{
  __shared__ short lsX[BM*64];
  __shared__ short lsG[BM*64];
  __shared__ short lsU[BM*64];
  __shared__ float lsWt[BM];

  const int bx = blockIdx.x;
  if (bx >= blk_start[E_NUM]) return;
  int e = 0;
  while (blk_start[e+1] <= bx) ++e;
  const int rb   = bx - blk_start[e];
  const int cb   = blockIdx.y;
  const int base = offsets[e];
  const int n_e  = offsets[e+1] - base;
  const int row0 = rb * BM;

  const int tid   = threadIdx.x;
  const int srow  = tid >> 2;
  const int scol  = (tid & 3) << 4;
  const int slot0 = (tid & 3) << 1;
  const int wsl0  = srow*64 + (((slot0  ) ^ (srow & 7)) << 3);
  const int wsl1  = srow*64 + (((slot0+1) ^ (srow & 7)) << 3);

  const bool tvalid = (row0 + srow) < n_e;
  int tok = 0;
  if (tvalid) tok = token_list[base + row0 + srow];
  const float* xsrc = hidden + (size_t)tok * H_DIM + scol;
  const size_t woff = (size_t)e * I_DIM * H_DIM + (size_t)(cb*128 + srow) * H_DIM + scol;
  const float* gsrc = w_gate + woff;
  const float* usrc = w_up   + woff;

  const int lane = tid & 63, wid = tid >> 6;
  const int wm = wid >> 2, wn = wid & 3;
  const int l15 = lane & 15, l4 = lane >> 4;

  f4v accg[4][2], accu[4][2];
  #pragma unroll
  for (int m=0;m<4;m++)
    #pragma unroll
    for (int n=0;n<2;n++){
      accg[m][n]=(f4v){0.f,0.f,0.f,0.f};
      accu[m][n]=(f4v){0.f,0.f,0.f,0.f};
    }

  for (int k0=0; k0<H_DIM; k0+=BK){
    f4v x0,x1,x2,x3;
    if (tvalid){
      x0 = *(const f4v*)(xsrc+k0);   x1 = *(const f4v*)(xsrc+k0+4);
      x2 = *(const f4v*)(xsrc+k0+8); x3 = *(const f4v*)(xsrc+k0+12);
    } else {
      x0=x1=x2=x3=(f4v){0.f,0.f,0.f,0.f};
    }
    f4v g0 = *(const f4v*)(gsrc+k0),   g1 = *(const f4v*)(gsrc+k0+4);
    f4v g2 = *(const f4v*)(gsrc+k0+8), g3 = *(const f4v*)(gsrc+k0+12);
    f4v u0 = *(const f4v*)(usrc+k0),   u1 = *(const f4v*)(usrc+k0+4);
    f4v u2 = *(const f4v*)(usrc+k0+8), u3 = *(const f4v*)(usrc+k0+12);
    __syncthreads();
    *(s8v*)&lsX[wsl0] = cvt8(x0,x1);  *(s8v*)&lsX[wsl1] = cvt8(x2,x3);
    *(s8v*)&lsG[wsl0] = cvt8(g0,g1);  *(s8v*)&lsG[wsl1] = cvt8(g2,g3);
    *(s8v*)&lsU[wsl0] = cvt8(u0,u1);  *(s8v*)&lsU[wsl1] = cvt8(u2,u3);
    __syncthreads();
    #pragma unroll
    for (int kk=0;kk<2;kk++){
      s8v af[4], bg[2], bu[2];
      #pragma unroll
      for (int m=0;m<4;m++){
        int r = wm*64 + m*16 + l15;
        int s = (kk*4 + l4) ^ (r & 7);
        af[m] = *(const s8v*)&lsX[r*64 + (s<<3)];
      }
      #pragma unroll
      for (int n=0;n<2;n++){
        int r = wn*32 + n*16 + l15;
        int s = (kk*4 + l4) ^ (r & 7);
        bg[n] = *(const s8v*)&lsG[r*64 + (s<<3)];
        bu[n] = *(const s8v*)&lsU[r*64 + (s<<3)];
      }
      #pragma unroll
      for (int m=0;m<4;m++)
        #pragma unroll
        for (int n=0;n<2;n++){
          accg[m][n] = __builtin_amdgcn_mfma_f32_16x16x32_bf16(af[m], bg[n], accg[m][n], 0,0,0);
          accu[m][n] = __builtin_amdgcn_mfma_f32_16x16x32_bf16(af[m], bu[n], accu[m][n], 0,0,0);
        }
    }
  }
  if (tid < BM) lsWt[tid] = ((row0+tid) < n_e) ? weight_list[base+row0+tid] : 0.f;
  __syncthreads();
  #pragma unroll
  for (int m=0;m<4;m++){
    #pragma unroll
    for (int i=0;i<4;i++){
      int r = wm*64 + m*16 + l4*4 + i;
      if (row0 + r < n_e){
        float wgt = lsWt[r];
        size_t hb = (size_t)(base+row0+r)*I_DIM + (size_t)cb*128;
        #pragma unroll
        for (int n=0;n<2;n++){
          int c = wn*32 + n*16 + l15;
          float g = accg[m][n][i], u = accu[m][n][i];
          float s = g / (1.f + __expf(-g));
          h_all[hb + c] = f2bf(s * u * wgt);
        }
      }
    }
  }
}

__launch_bounds__(512, 2)
__global__ void ffn2_kernel(const short* __restrict__ h_all,
                            const float* __restrict__ w_down,
                            const int*   __restrict__ token_list,
                            const int*   __restrict__ offsets,
                            const int*   __restrict__ blk_start,
                            float*       __restrict__ out)
{
  __shared__ short lsA[BM*64];
  __shared__ short lsB[BM*64];
  __shared__ int   lsT[BM];

  const int bx = blockIdx.x;
  if (bx >= blk_start[E_NUM]) return;
  int e = 0;
  while (blk_start[e+1] <= bx) ++e;
  const int rb   = bx - blk_start[e];
  const int cb   = blockIdx.y;
  const int base = offsets[e];
  const int n_e  = offsets[e+1] - base;
  const int row0 = rb * BM;

  const int tid   = threadIdx.x;
  const int srow  = tid >> 2;
  const int slot0 = (tid & 3) << 1;
  const int wsl0  = srow*64 + (((slot0  ) ^ (srow & 7)) << 3);
  const int wsl1  = srow*64 + (((slot0+1) ^ (srow & 7)) << 3);

  int arow = base + row0 + srow;
  if (arow >= S_ASN) arow = S_ASN - 1;
  const short* asrc = h_all + (size_t)arow*I_DIM + ((tid&3)<<4);
  const float* bsrc = w_down + (size_t)e*H_DIM*I_DIM
                    + (size_t)(cb*128 + srow)*I_DIM + ((tid&3)<<4);

  const int lane = tid & 63, wid = tid >> 6;
  const int wm = wid >> 2, wn = wid & 3;
  const int l15 = lane & 15, l4 = lane >> 4;

  f4v acc[4][2];
  #pragma unroll
  for (int m=0;m<4;m++)
    #pragma unroll
    for (int n=0;n<2;n++) acc[m][n]=(f4v){0.f,0.f,0.f,0.f};

  for (int k0=0; k0<I_DIM; k0+=BK){
    s8v alo = *(const s8v*)(asrc + k0);
    s8v ahi = *(const s8v*)(asrc + k0 + 8);
    f4v b0 = *(const f4v*)(bsrc+k0),   b1 = *(const f4v*)(bsrc+k0+4);
    f4v b2 = *(const f4v*)(bsrc+k0+8), b3 = *(const f4v*)(bsrc+k0+12);
    __syncthreads();
    *(s8v*)&lsA[wsl0] = alo;          *(s8v*)&lsA[wsl1] = ahi;
    *(s8v*)&lsB[wsl0] = cvt8(b0,b1);  *(s8v*)&lsB[wsl1] = cvt8(b2,b3);
    __syncthreads();
    #pragma unroll
    for (int kk=0;kk<2;kk++){
      s8v af[4], bf[2];
      #pragma unroll
      for (int m=0;m<4;m++){
        int r = wm*64 + m*16 + l15;
        int s = (kk*4 + l4) ^ (r & 7);
        af[m] = *(const s8v*)&lsA[r*64 + (s<<3)];
      }
      #pragma unroll
      for (int n=0;n<2;n++){
        int r = wn*32 + n*16 + l15;
        int s = (kk*4 + l4) ^ (r & 7);
        bf[n] = *(const s8v*)&lsB[r*64 + (s<<3)];
      }
      #pragma unroll
      for (int m=0;m<4;m++)
        #pragma unroll
        for (int n=0;n<2;n++)
          acc[m][n] = __builtin_amdgcn_mfma_f32_16x16x32_bf16(af[m], bf[n], acc[m][n], 0,0,0);
    }
  }
  if (tid < BM) lsT[tid] = ((row0+tid) < n_e) ? token_list[base+row0+tid] : -1;
  __syncthreads();
  #pragma unroll
  for (int m=0;m<4;m++){
    #pragma unroll
    for (int i=0;i<4;i++){
      int r = wm*64 + m*16 + l4*4 + i;
      int tk = lsT[r];
      if (tk >= 0){
        #pragma unroll
        for (int n=0;n<2;n++){
          int c = cb*128 + wn*32 + n*16 + l15;
          atomicAdd(&out[(size_t)tk*H_DIM + c], acc[m][n][i]);
        }
      }
    }
  }
}

/* ---------------- launch --------------------------------------------------- */
extern "C" void kernel_launch(void* const* d_in, const int* in_sizes, int n_in,
                              void* d_out, int out_size, void* d_ws, size_t ws_size,
                              hipStream_t stream)
{
  const float* hidden = (const float*)d_in[0];
  const float* gate_w = (const float*)d_in[1];
  const float* bias   = (const float*)d_in[2];
  const float* w_gate = (const float*)d_in[3];
  const float* w_up   = (const float*)d_in[4];
  const float* w_down = (const float*)d_in[5];
  float* out = (float*)d_out;

  char* ws = (char*)d_ws;
  size_t off = 0;
  #define WALLOC(bytes) (ws + off); off += (((size_t)(bytes)) + 255) & ~(size_t)255
  double* logits    = (double*)WALLOC((size_t)T_TOK*E_NUM*8);
  int*    topk_idx  = (int*)   WALLOC((size_t)T_TOK*TOPK*4);
  float*  topk_w    = (float*) WALLOC((size_t)T_TOK*TOPK*4);
  int*    counts    = (int*)   WALLOC(256);
  int*    cursor    = (int*)   WALLOC(256);
  int*    offsets   = (int*)   WALLOC(512);
  int*    blk_st    = (int*)   WALLOC(512);
  int*    token_l   = (int*)   WALLOC((size_t)S_ASN*4);
  float*  weight_l  = (float*) WALLOC((size_t)S_ASN*4);
  int*    pos_l     = (int*)   WALLOC((size_t)S_ASN*4);
  short*  h_all     = (short*) WALLOC((size_t)S_ASN*I_DIM*2);
  const size_t base_need = off;
  short*  hid_bf    = (short*) WALLOC((size_t)T_TOK*H_DIM*2);      /* 33.55 MB */
  short*  wg_bf     = (short*) WALLOC((size_t)E_NUM*I_DIM*H_DIM*2);/* 100.66 MB */
  short*  wu_bf     = (short*) WALLOC((size_t)E_NUM*I_DIM*H_DIM*2);
  short*  wd_bf     = (short*) WALLOC((size_t)E_NUM*H_DIM*I_DIM*2);
  const size_t fast_need = off;
  #undef WALLOC
  /* y (S_ASN*512*2 = 134,217,728 B) aliases hid_bf+wg_bf (33,554,432 +
     100,663,296 = 134,217,728 B exactly) — both dead once ffn1 completes. */
  short* y_all = hid_bf;

  const bool fast = (ws_size >= fast_need);
  if (ws_size < base_need) return;

  hipMemsetAsync(counts, 0, 512, stream);                 /* counts + cursor */

  gate_kernel   <<<T_TOK/64,  256, 0, stream>>>(hidden, gate_w, logits,
                                                fast ? hid_bf : (short*)0);
  route_kernel  <<<T_TOK/256, 256, 0, stream>>>(logits, bias, topk_idx, topk_w, counts);
  scan_kernel   <<<1, 64, 0, stream>>>(counts, offsets, blk_st);
  scatter_kernel<<<T_TOK/256, 256, 0, stream>>>(topk_idx, topk_w, offsets, cursor,
                                                token_l, weight_l, pos_l);
  if (fast){
    long n8w = (long)E_NUM*I_DIM*H_DIM/8;   /* 6,291,456 = 3072*256*8 exactly */
    cast_kernel<<<3072, 256, 0, stream>>>(w_gate, wg_bf, n8w);
    cast_kernel<<<3072, 256, 0, stream>>>(w_up,   wu_bf, n8w);
    cast_kernel<<<3072, 256, 0, stream>>>(w_down, wd_bf, n8w);
    dim3 g1(MAXBLK, I_DIM/128);  /* 1088 x 6 */
    ffn1_fast<<<g1, 512, 0, stream>>>(hid_bf, wg_bf, wu_bf, token_l, weight_l,
                                      offsets, blk_st, h_all);
    dim3 g2(MAXBLK, 4);          /* 1088 x 4 per half (BN=128) */
    for (int half = 0; half < 2; ++half){
      ffn2y_fast<<<g2, 256, 0, stream>>>(h_all, wd_bf, offsets, blk_st,
                                         y_all, half);
      combine_kernel<<<T_TOK/2, 256, 0, stream>>>(y_all, pos_l, out, half);
    }
  } else {
    hipMemsetAsync(out, 0, (size_t)T_TOK*H_DIM*4, stream);
    dim3 g1(MAXBLK, I_DIM/128);
    ffn1_kernel<<<g1, 512, 0, stream>>>(hidden, w_gate, w_up, token_l, weight_l,
                                        offsets, blk_st, h_all);
    dim3 g2(MAXBLK, H_DIM/128);
    ffn2_kernel<<<g2, 512, 0, stream>>>(h_all, w_down, token_l, offsets, blk_st, out);
  }
}

// Round 10
// 1587.936 us; speedup vs baseline: 1.2935x; 1.0687x over previous
//
#include <hip/hip_runtime.h>
#include <hip/hip_bf16.h>
#include <math.h>

#define T_TOK 16384
#define H_DIM 1024
#define E_NUM 64
#define I_DIM 768
#define TOPK  8
#define NGRP  8
#define KGRP  4
#define S_ASN (T_TOK*TOPK)        /* 131072 assignments */
#define BM 128
#define BK 64
#define MAXBLK (S_ASN/BM + E_NUM) /* 1088: upper bound of sum(ceil(n_e/BM)) */

typedef __attribute__((ext_vector_type(4))) float f4v;
typedef __attribute__((ext_vector_type(8))) short s8v;
typedef __attribute__((ext_vector_type(4))) unsigned short u4sv;

#define GLDS16(g, l) __builtin_amdgcn_global_load_lds( \
    (const __attribute__((address_space(1))) void*)(g), \
    (__attribute__((address_space(3))) void*)(l), 16, 0, 0)

static __device__ __forceinline__ short f2bf(float f){
  union { float f; unsigned u; } a; a.f = f;
  unsigned u = a.u;
  unsigned r = (u + 0x7fffu + ((u >> 16) & 1u)) >> 16;  /* RNE */
  return (short)r;
}
static __device__ __forceinline__ float bf2f(unsigned short h){
  union { unsigned u; float f; } a; a.u = ((unsigned)h) << 16; return a.f;
}
static __device__ __forceinline__ s8v cvt8(f4v a, f4v b){
  s8v r;
  r[0]=f2bf(a[0]); r[1]=f2bf(a[1]); r[2]=f2bf(a[2]); r[3]=f2bf(a[3]);
  r[4]=f2bf(b[0]); r[5]=f2bf(b[1]); r[6]=f2bf(b[2]); r[7]=f2bf(b[3]);
  return r;
}

/* ---------------- fp32 -> bf16 bulk cast (non-temporal streaming) ---------- */
__launch_bounds__(256)
__global__ void cast_kernel(const float* __restrict__ src,
                            short* __restrict__ dst, long n8)
{
  long i = (long)blockIdx.x*blockDim.x + threadIdx.x;
  long stride = (long)gridDim.x*blockDim.x;
  for (; i < n8; i += stride){
    f4v a = __builtin_nontemporal_load((const f4v*)(src + i*8));
    f4v b = __builtin_nontemporal_load((const f4v*)(src + i*8 + 4));
    __builtin_nontemporal_store(cvt8(a, b), (s8v*)(dst + i*8));
  }
}

/* ---------------- gate logits + hidden bf16 side-output -------------------- */
__launch_bounds__(256)
__global__ void gate_kernel(const float* __restrict__ hidden,
                            const float* __restrict__ gate_w,
                            double* __restrict__ logits,
                            short*  __restrict__ hb)   /* may be null */
{
  __shared__ float sX[64][33];
  __shared__ float sW[64][33];
  const int tid  = threadIdx.x;
  const int t0   = blockIdx.x * 64;
  const int srow = tid >> 2;
  const int scol = (tid & 3) * 8;
  const int tx = tid & 15, ty = tid >> 4;
  double acc[4][4];
  #pragma unroll
  for (int i=0;i<4;i++)
    #pragma unroll
    for (int j=0;j<4;j++) acc[i][j]=0.0;

  for (int k0=0;k0<H_DIM;k0+=32){
    f4v a0 = *(const f4v*)&hidden[(size_t)(t0+srow)*H_DIM + k0 + scol];
    f4v a1 = *(const f4v*)&hidden[(size_t)(t0+srow)*H_DIM + k0 + scol + 4];
    f4v b0 = *(const f4v*)&gate_w[(size_t)srow*H_DIM + k0 + scol];
    f4v b1 = *(const f4v*)&gate_w[(size_t)srow*H_DIM + k0 + scol + 4];
    if (hb)  /* bf16 side-output: each element written exactly once */
      *(s8v*)&hb[(size_t)(t0+srow)*H_DIM + k0 + scol] = cvt8(a0, a1);
    __syncthreads();
    #pragma unroll
    for (int j=0;j<4;j++){
      sX[srow][scol+j]   = a0[j];  sX[srow][scol+4+j] = a1[j];
      sW[srow][scol+j]   = b0[j];  sW[srow][scol+4+j] = b1[j];
    }
    __syncthreads();
    #pragma unroll
    for (int kk=0;kk<32;kk++){
      float xv[4], wv[4];
      #pragma unroll
      for (int i=0;i<4;i++){ xv[i]=sX[ty*4+i][kk]; wv[i]=sW[tx*4+i][kk]; }
      #pragma unroll
      for (int i=0;i<4;i++)
        #pragma unroll
        for (int j=0;j<4;j++)
          acc[i][j] += (double)xv[i] * (double)wv[j];
    }
  }
  #pragma unroll
  for (int i=0;i<4;i++)
    #pragma unroll
    for (int j=0;j<4;j++)
      logits[(size_t)(t0+ty*4+i)*E_NUM + tx*4+j] = acc[i][j];
}

/* ---------------- routing: grouped top-k in fp64 --------------------------- */
__global__ void route_kernel(const double* __restrict__ logits,
                             const float*  __restrict__ bias,
                             int*   __restrict__ topk_idx,
                             float* __restrict__ topk_w,
                             int*   __restrict__ counts)
{
  const int t = blockIdx.x * blockDim.x + threadIdx.x;
  if (t >= T_TOK) return;
  const double* lg = logits + (size_t)t * E_NUM;
  double sc[E_NUM], sch[E_NUM];
  for (int e2=0;e2<E_NUM;e2++){
    double s = 1.0 / (1.0 + exp(-lg[e2]));
    sc[e2]  = s;
    sch[e2] = s + (double)bias[e2];
  }
  double gs[NGRP];
  for (int g=0;g<NGRP;g++){
    double m1=-1e300, m2=-1e300;
    for (int j=0;j<8;j++){
      double v = sch[g*8+j];
      if (v > m1){ m2 = m1; m1 = v; } else if (v > m2){ m2 = v; }
    }
    gs[g] = m1 + m2;
  }
  unsigned gsel = 0;
  for (int r=0;r<KGRP;r++){
    int best = 0; double bv = -1.0e308;
    for (int g=0;g<NGRP;g++)
      if (!((gsel>>g)&1u) && gs[g] > bv){ bv = gs[g]; best = g; }
    gsel |= 1u << best;
  }
  unsigned long long used = 0ULL;
  double wsum = 0.0;
  int sel[TOPK]; double w[TOPK];
  for (int r=0;r<TOPK;r++){
    int best = 0; double bv = -1.0e308;
    for (int e2=0;e2<E_NUM;e2++){
      if ((used>>e2)&1ULL) continue;
      if (!((gsel>>(e2>>3))&1u)) continue;
      if (sch[e2] > bv){ bv = sch[e2]; best = e2; }
    }
    used |= 1ULL << best;
    sel[r] = best;
    w[r]   = sc[best];
    wsum  += w[r];
  }
  double inv = 1.0 / (wsum + 1e-20);
  for (int r=0;r<TOPK;r++){
    topk_idx[(size_t)t*TOPK + r] = sel[r];
    topk_w  [(size_t)t*TOPK + r] = (float)(w[r]*inv);
    atomicAdd(&counts[sel[r]], 1);
  }
}

/* ---------------- prefix sums --------------------------------------------- */
__global__ void scan_kernel(const int* __restrict__ counts,
                            int* __restrict__ offsets,
                            int* __restrict__ blk_start)
{
  if (threadIdx.x == 0 && blockIdx.x == 0){
    int off = 0, blk = 0;
    for (int e=0;e<E_NUM;e++){
      offsets[e] = off; blk_start[e] = blk;
      off += counts[e];
      blk += (counts[e] + BM - 1) / BM;
    }
    offsets[E_NUM] = off; blk_start[E_NUM] = blk;
  }
}

/* ---------------- scatter token lists + inverse positions ------------------ */
__global__ void scatter_kernel(const int* __restrict__ topk_idx,
                               const float* __restrict__ topk_w,
                               const int* __restrict__ offsets,
                               int* __restrict__ cursor,
                               int* __restrict__ token_list,
                               float* __restrict__ weight_list,
                               int* __restrict__ pos_list)
{
  const int t = blockIdx.x*blockDim.x + threadIdx.x;
  if (t >= T_TOK) return;
  for (int r=0;r<TOPK;r++){
    int   e2 = topk_idx[(size_t)t*TOPK + r];
    float wv = topk_w [(size_t)t*TOPK + r];
    int p = atomicAdd(&cursor[e2], 1);
    token_list [offsets[e2] + p] = t;
    weight_list[offsets[e2] + p] = wv;
    pos_list[(size_t)t*TOPK + r] = offsets[e2] + p;
  }
}

/* ======================= FAST PATH (bf16 + global_load_lds) ================ */
/* LDS written LINEARLY by global_load_lds; XOR swizzle lives in the per-lane
   GLOBAL source address (inverse) and in the ds_read (forward):
   LDS slot (row, sl) holds global 16B-slot (sl ^ (row&7)).
   Grid axes: blockIdx.x = column-chunk (FAST: dispatch-adjacent blocks share
   one A-tile / one h_all row-block), blockIdx.y = row-block.                 */

/* ffn1: h = silu(X Wg^T) * (X Wu^T) * w.
   512 thr / 8 waves, BM=128, BN=128, BK=64. Wave-tile 64x32 (x2 for g,u). */
__launch_bounds__(512, 4)
__global__ void ffn1_fast(const short* __restrict__ hid_bf,
                          const short* __restrict__ wg_bf,
                          const short* __restrict__ wu_bf,
                          const int*   __restrict__ token_list,
                          const float* __restrict__ weight_list,
                          const int*   __restrict__ offsets,
                          const int*   __restrict__ blk_start,
                          short*       __restrict__ h_all)
{
  __shared__ short lsX[128*64];
  __shared__ short lsG[128*64];
  __shared__ short lsU[128*64];
  __shared__ float lsWt[128];

  const int bx = blockIdx.y;                 /* row-block index */
  if (bx >= blk_start[E_NUM]) return;
  int e = 0;
  while (blk_start[e+1] <= bx) ++e;
  const int rb   = bx - blk_start[e];
  const int cb   = blockIdx.x;               /* 0..5 : 128-col chunk of I */
  const int base = offsets[e];
  const int n_e  = offsets[e+1] - base;
  const int row0 = rb * BM;

  const int tid = threadIdx.x;
  const int lane = tid & 63, wid = tid >> 6;   /* 8 waves */
  const int wm = wid >> 2, wn = wid & 3;       /* 2 x 4 wave grid */
  const int l15 = lane & 15, l4 = lane >> 4;

  if (tid < BM) lsWt[tid] = ((row0+tid) < n_e) ? weight_list[base+row0+tid] : 0.f;

  const short* srcA[2];
  #pragma unroll
  for (int i=0;i<2;i++){
    int s_lin = i*512 + tid;
    int row = s_lin >> 3, sl = s_lin & 7;
    int asn = base + row0 + row; if (asn >= S_ASN) asn = S_ASN-1;
    int tok = token_list[asn];
    srcA[i] = hid_bf + (size_t)tok*H_DIM + ((sl ^ (row&7))<<3);
  }
  const short* srcG[2]; const short* srcU[2];
  #pragma unroll
  for (int i=0;i<2;i++){
    int s_lin = i*512 + tid;
    int row = s_lin >> 3, sl = s_lin & 7;
    size_t wrow = ((size_t)e*I_DIM + cb*128 + row)*H_DIM + ((sl ^ (row&7))<<3);
    srcG[i] = wg_bf + wrow;
    srcU[i] = wu_bf + wrow;
  }
  short* dstA0 = lsX + wid*512;
  short* dstG0 = lsG + wid*512;
  short* dstU0 = lsU + wid*512;

  f4v accg[4][2], accu[4][2];
  #pragma unroll
  for (int m=0;m<4;m++)
    #pragma unroll
    for (int n=0;n<2;n++){
      accg[m][n]=(f4v){0.f,0.f,0.f,0.f};
      accu[m][n]=(f4v){0.f,0.f,0.f,0.f};
    }

  for (int k0=0; k0<H_DIM; k0+=BK){
    __syncthreads();
    #pragma unroll
    for (int i=0;i<2;i++) GLDS16(srcA[i]+k0, dstA0 + i*4096);
    #pragma unroll
    for (int i=0;i<2;i++) GLDS16(srcG[i]+k0, dstG0 + i*4096);
    #pragma unroll
    for (int i=0;i<2;i++) GLDS16(srcU[i]+k0, dstU0 + i*4096);
    __syncthreads();
    #pragma unroll
    for (int kk=0;kk<2;kk++){
      s8v af[4], bg[2], bu[2];
      #pragma unroll
      for (int m=0;m<4;m++){
        int r = wm*64 + m*16 + l15;
        int s = (kk*4 + l4) ^ (r & 7);
        af[m] = *(const s8v*)&lsX[r*64 + (s<<3)];
      }
      #pragma unroll
      for (int n=0;n<2;n++){
        int r = wn*32 + n*16 + l15;
        int s = (kk*4 + l4) ^ (r & 7);
        bg[n] = *(const s8v*)&lsG[r*64 + (s<<3)];
        bu[n] = *(const s8v*)&lsU[r*64 + (s<<3)];
      }
      #pragma unroll
      for (int m=0;m<4;m++)
        #pragma unroll
        for (int n=0;n<2;n++){
          accg[m][n] = __builtin_amdgcn_mfma_f32_16x16x32_bf16(af[m], bg[n], accg[m][n], 0,0,0);
          accu[m][n] = __builtin_amdgcn_mfma_f32_16x16x32_bf16(af[m], bu[n], accu[m][n], 0,0,0);
        }
    }
  }
  #pragma unroll
  for (int m=0;m<4;m++){
    #pragma unroll
    for (int i=0;i<4;i++){
      int r = wm*64 + m*16 + l4*4 + i;
      if (row0 + r < n_e){
        float wgt = lsWt[r];
        size_t hb = (size_t)(base+row0+r)*I_DIM + (size_t)cb*128;
        #pragma unroll
        for (int n=0;n<2;n++){
          int c = wn*32 + n*16 + l15;
          float g = accg[m][n][i], u = accu[m][n][i];
          float s = g / (1.f + __expf(-g));
          __builtin_nontemporal_store((short)f2bf(s * u * wgt), &h_all[hb + c]);
        }
      }
    }
  }
}

/* ffn2y: y[asn, cols] = h_all @ Wd^T  (dense bf16 writes, NO atomics).
   Round-4 verified GEMM config: 256 thr / 4 waves (2x2), BM=128, BN=128,
   BK=64, wave-tile 64x64, acc[4][4].  blockIdx.x = cby (fast), .y = rowblk.
   Single-pass mode: cb0=0, gridDim.x=8, ystride=1024.
   Half mode:        cb0 in {0,1}, gridDim.x=4, ystride=512.                 */
__launch_bounds__(256, 3)
__global__ void ffn2y_fast(const short* __restrict__ h_all,
                           const short* __restrict__ wd_bf,
                           const int*   __restrict__ offsets,
                           const int*   __restrict__ blk_start,
                           short*       __restrict__ y,
                           int          cb0,
                           int          ystride)
{
  __shared__ short lsA[128*64];
  __shared__ short lsB[128*64];

  const int bx = blockIdx.y;                 /* row-block index */
  if (bx >= blk_start[E_NUM]) return;
  int e = 0;
  while (blk_start[e+1] <= bx) ++e;
  const int rb   = bx - blk_start[e];
  const int cby  = blockIdx.x;               /* col-chunk within this launch */
  const int cbg  = cb0*4 + cby;              /* global 128-col chunk of H */
  const int base = offsets[e];
  const int n_e  = offsets[e+1] - base;
  const int row0 = rb * BM;

  const int tid = threadIdx.x;
  const int lane = tid & 63, wid = tid >> 6;
  const int wm = wid >> 1, wn = wid & 1;     /* 2 x 2 wave grid */
  const int l15 = lane & 15, l4 = lane >> 4;

  const short* srcA[4]; const short* srcB[4];
  #pragma unroll
  for (int i=0;i<4;i++){
    int s_lin = i*256 + tid;
    int row = s_lin >> 3, sl = s_lin & 7;
    int arow = base + row0 + row; if (arow >= S_ASN) arow = S_ASN-1;
    srcA[i] = h_all + (size_t)arow*I_DIM + ((sl ^ (row&7))<<3);
    srcB[i] = wd_bf + ((size_t)e*H_DIM + cbg*128 + row)*I_DIM + ((sl ^ (row&7))<<3);
  }
  short* dstA0 = lsA + wid*512;
  short* dstB0 = lsB + wid*512;

  f4v acc[4][4];
  #pragma unroll
  for (int m=0;m<4;m++)
    #pragma unroll
    for (int n=0;n<4;n++) acc[m][n]=(f4v){0.f,0.f,0.f,0.f};

  for (int k0=0; k0<I_DIM; k0+=BK){
    __syncthreads();
    #pragma unroll
    for (int i=0;i<4;i++) GLDS16(srcA[i]+k0, dstA0 + i*2048);
    #pragma unroll
    for (int i=0;i<4;i++) GLDS16(srcB[i]+k0, dstB0 + i*2048);
    __syncthreads();
    #pragma unroll
    for (int kk=0;kk<2;kk++){
      s8v af[4], bf[4];
      #pragma unroll
      for (int m=0;m<4;m++){
        int r = wm*64 + m*16 + l15;
        int s = (kk*4 + l4) ^ (r & 7);
        af[m] = *(const s8v*)&lsA[r*64 + (s<<3)];
      }
      #pragma unroll
      for (int n=0;n<4;n++){
        int r = wn*64 + n*16 + l15;
        int s = (kk*4 + l4) ^ (r & 7);
        bf[n] = *(const s8v*)&lsB[r*64 + (s<<3)];
      }
      #pragma unroll
      for (int m=0;m<4;m++)
        #pragma unroll
        for (int n=0;n<4;n++)
          acc[m][n] = __builtin_amdgcn_mfma_f32_16x16x32_bf16(af[m], bf[n], acc[m][n], 0,0,0);
    }
  }
  #pragma unroll
  for (int m=0;m<4;m++){
    #pragma unroll
    for (int i=0;i<4;i++){
      int r = wm*64 + m*16 + l4*4 + i;
      if (row0 + r < n_e){
        size_t yb = (size_t)(base+row0+r)*ystride + (size_t)cby*128;
        #pragma unroll
        for (int n=0;n<4;n++){
          int c = wn*64 + n*16 + l15;
          y[yb + c] = f2bf(acc[m][n][i]);
        }
      }
    }
  }
}

/* combine: out[t, cb0*512 + c] = sum_r y[pos[t,r], ybase + c] (fixed r order) */
__launch_bounds__(256)
__global__ void combine_kernel(const short* __restrict__ y,
                               const int*   __restrict__ pos,
                               float*       __restrict__ out,
                               int cb0, int ystride, int ybase)
{
  const int tid = threadIdx.x;
  const int t = blockIdx.x*2 + (tid >> 7);
  const int c = (tid & 127) * 4;
  const int* pp = pos + (size_t)t*TOPK;
  float s0=0.f, s1=0.f, s2=0.f, s3=0.f;
  #pragma unroll
  for (int r=0;r<TOPK;r++){
    int row = pp[r];
    u4sv v = *(const u4sv*)&y[(size_t)row*ystride + ybase + c];
    s0 += bf2f(v[0]); s1 += bf2f(v[1]); s2 += bf2f(v[2]); s3 += bf2f(v[3]);
  }
  f4v o = {s0,s1,s2,s3};
  *(f4v*)&out[(size_t)t*H_DIM + (size_t)cb0*512 + c] = o;
}

/* ======================= SLOW FALLBACK (round-1, fp32 reg-staged) ========== */
__launch_bounds__(512, 2)
__global__ void ffn1_kernel(const float* __restrict__ hidden,
                            const float* __restrict__ w_gate,
                            const float* __restrict__ w_up,
                            const int*   __restrict__ token_list,
                            const float* __restrict__ weight_list,
                            const int*   __restrict__ offsets,
                            const int*   __restrict__ blk_start,
                            short*       __restrict__ h_all)
{
  __shared__ short lsX[BM*64];
  __shared__ short lsG[BM*64];
  __shared__ short lsU[BM*64];
  __shared__ float lsWt[BM];

  const int bx = blockIdx.x;
  if (bx >= blk_start[E_NUM]) return;
  int e = 0;
  while (blk_start[e+1] <= bx) ++e;
  const int rb   = bx - blk_start[e];
  const int cb   = blockIdx.y;
  const int base = offsets[e];
  const int n_e  = offsets[e+1] - base;
  const int row0 = rb * BM;

  const int tid   = threadIdx.x;
  const int srow  = tid >> 2;
  const int scol  = (tid & 3) << 4;
  const int slot0 = (tid & 3) << 1;
  const int wsl0  = srow*64 + (((slot0  ) ^ (srow & 7)) << 3);
  const int wsl1  = srow*64 + (((slot0+1) ^ (srow & 7)) << 3);

  const bool tvalid = (row0 + srow) < n_e;
  int tok = 0;
  if (tvalid) tok = token_list[base + row0 + srow];
  const float* xsrc = hidden + (size_t)tok * H_DIM + scol;
  const size_t woff = (size_t)e * I_DIM * H_DIM + (size_t)(cb*128 + srow) * H_DIM + scol;
  const float* gsrc = w_gate + woff;
  const float* usrc = w_up   + woff;

  const int lane = tid & 63, wid = tid >> 6;
  const int wm = wid >> 2, wn = wid & 3;
  const int l15 = lane & 15, l4 = lane >> 4;

  f4v accg[4][2], accu[4][2];
  #pragma unroll
  for (int m=0;m<4;m++)
    #pragma unroll
    for (int n=0;n<2;n++){
      accg[m][n]=(f4v){0.f,0.f,0.f,0.f};
      accu[m][n]=(f4v){0.f,0.f,0.f,0.f};
    }

  for (int k0=0; k0<H_DIM; k0+=BK){
    f4v x0,x1,x2,x3;
    if (tvalid){
      x0 = *(const f4v*)(xsrc+k0);   x1 = *(const f4v*)(xsrc+k0+4);
      x2 = *(const f4v*)(xsrc+k0+8); x3 = *(const f4v*)(xsrc+k0+12);
    } else {
      x0=x1=x2=x3=(f4v){0.f,0.f,0.f,0.f};
    }
    f4v g0 = *(const f4v*)(gsrc+k0),   g1 = *(const f4v*)(gsrc+k0+4);
    f4v g2 = *(const f4v*)(gsrc+k0+8), g3 = *(const f4v*)(gsrc+k0+12);
    f4v u0 = *(const f4v*)(usrc+k0),   u1 = *(const f4v*)(usrc+k0+4);
    f4v u2 = *(const f4v*)(usrc+k0+8), u3 = *(const f4v*)(usrc+k0+12);
    __syncthreads();
    *(s8v*)&lsX[wsl0] = cvt8(x0,x1);  *(s8v*)&lsX[wsl1] = cvt8(x2,x3);
    *(s8v*)&lsG[wsl0] = cvt8(g0,g1);  *(s8v*)&lsG[wsl1] = cvt8(g2,g3);
    *(s8v*)&lsU[wsl0] = cvt8(u0,u1);  *(s8v*)&lsU[wsl1] = cvt8(u2,u3);
    __syncthreads();
    #pragma unroll
    for (int kk=0;kk<2;kk++){
      s8v af[4], bg[2], bu[2];
      #pragma unroll
      for (int m=0;m<4;m++){
        int r = wm*64 + m*16 + l15;
        int s = (kk*4 + l4) ^ (r & 7);
        af[m] = *(const s8v*)&lsX[r*64 + (s<<3)];
      }
      #pragma unroll
      for (int n=0;n<2;n++){
        int r = wn*32 + n*16 + l15;
        int s = (kk*4 + l4) ^ (r & 7);
        bg[n] = *(const s8v*)&lsG[r*64 + (s<<3)];
        bu[n] = *(const s8v*)&lsU[r*64 + (s<<3)];
      }
      #pragma unroll
      for (int m=0;m<4;m++)
        #pragma unroll
        for (int n=0;n<2;n++){
          accg[m][n] = __builtin_amdgcn_mfma_f32_16x16x32_bf16(af[m], bg[n], accg[m][n], 0,0,0);
          accu[m][n] = __builtin_amdgcn_mfma_f32_16x16x32_bf16(af[m], bu[n], accu[m][n], 0,0,0);
        }
    }
  }
  if (tid < BM) lsWt[tid] = ((row0+tid) < n_e) ? weight_list[base+row0+tid] : 0.f;
  __syncthreads();
  #pragma unroll
  for (int m=0;m<4;m++){
    #pragma unroll
    for (int i=0;i<4;i++){
      int r = wm*64 + m*16 + l4*4 + i;
      if (row0 + r < n_e){
        float wgt = lsWt[r];
        size_t hb = (size_t)(base+row0+r)*I_DIM + (size_t)cb*128;
        #pragma unroll
        for (int n=0;n<2;n++){
          int c = wn*32 + n*16 + l15;
          float g = accg[m][n][i], u = accu[m][n][i];
          float s = g / (1.f + __expf(-g));
          h_all[hb + c] = f2bf(s * u * wgt);
        }
      }
    }
  }
}

__launch_bounds__(512, 2)
__global__ void ffn2_kernel(const short* __restrict__ h_all,
                            const float* __restrict__ w_down,
                            const int*   __restrict__ token_list,
                            const int*   __restrict__ offsets,
                            const int*   __restrict__ blk_start,
                            float*       __restrict__ out)
{
  __shared__ short lsA[BM*64];
  __shared__ short lsB[BM*64];
  __shared__ int   lsT[BM];

  const int bx = blockIdx.x;
  if (bx >= blk_start[E_NUM]) return;
  int e = 0;
  while (blk_start[e+1] <= bx) ++e;
  const int rb   = bx - blk_start[e];
  const int cb   = blockIdx.y;
  const int base = offsets[e];
  const int n_e  = offsets[e+1] - base;
  const int row0 = rb * BM;

  const int tid   = threadIdx.x;
  const int srow  = tid >> 2;
  const int slot0 = (tid & 3) << 1;
  const int wsl0  = srow*64 + (((slot0  ) ^ (srow & 7)) << 3);
  const int wsl1  = srow*64 + (((slot0+1) ^ (srow & 7)) << 3);

  int arow = base + row0 + srow;
  if (arow >= S_ASN) arow = S_ASN - 1;
  const short* asrc = h_all + (size_t)arow*I_DIM + ((tid&3)<<4);
  const float* bsrc = w_down + (size_t)e*H_DIM*I_DIM
                    + (size_t)(cb*128 + srow)*I_DIM + ((tid&3)<<4);

  const int lane = tid & 63, wid = tid >> 6;
  const int wm = wid >> 2, wn = wid & 3;
  const int l15 = lane & 15, l4 = lane >> 4;

  f4v acc[4][2];
  #pragma unroll
  for (int m=0;m<4;m++)
    #pragma unroll
    for (int n=0;n<2;n++) acc[m][n]=(f4v){0.f,0.f,0.f,0.f};

  for (int k0=0; k0<I_DIM; k0+=BK){
    s8v alo = *(const s8v*)(asrc + k0);
    s8v ahi = *(const s8v*)(asrc + k0 + 8);
    f4v b0 = *(const f4v*)(bsrc+k0),   b1 = *(const f4v*)(bsrc+k0+4);
    f4v b2 = *(const f4v*)(bsrc+k0+8), b3 = *(const f4v*)(bsrc+k0+12);
    __syncthreads();
    *(s8v*)&lsA[wsl0] = alo;          *(s8v*)&lsA[wsl1] = ahi;
    *(s8v*)&lsB[wsl0] = cvt8(b0,b1);  *(s8v*)&lsB[wsl1] = cvt8(b2,b3);
    __syncthreads();
    #pragma unroll
    for (int kk=0;kk<2;kk++){
      s8v af[4], bf[2];
      #pragma unroll
      for (int m=0;m<4;m++){
        int r = wm*64 + m*16 + l15;
        int s = (kk*4 + l4) ^ (r & 7);
        af[m] = *(const s8v*)&lsA[r*64 + (s<<3)];
      }
      #pragma unroll
      for (int n=0;n<2;n++){
        int r = wn*32 + n*16 + l15;
        int s = (kk*4 + l4) ^ (r & 7);
        bf[n] = *(const s8v*)&lsB[r*64 + (s<<3)];
      }
      #pragma unroll
      for (int m=0;m<4;m++)
        #pragma unroll
        for (int n=0;n<2;n++)
          acc[m][n] = __builtin_amdgcn_mfma_f32_16x16x32_bf16(af[m], bf[n], acc[m][n], 0,0,0);
    }
  }
  if (tid < BM) lsT[tid] = ((row0+tid) < n_e) ? token_list[base+row0+tid] : -1;
  __syncthreads();
  #pragma unroll
  for (int m=0;m<4;m++){
    #pragma unroll
    for (int i=0;i<4;i++){
      int r = wm*64 + m*16 + l4*4 + i;
      int tk = lsT[r];
      if (tk >= 0){
        #pragma unroll
        for (int n=0;n<2;n++){
          int c = cb*128 + wn*32 + n*16 + l15;
          atomicAdd(&out[(size_t)tk*H_DIM + c], acc[m][n][i]);
        }
      }
    }
  }
}

/* ---------------- launch --------------------------------------------------- */
extern "C" void kernel_launch(void* const* d_in, const int* in_sizes, int n_in,
                              void* d_out, int out_size, void* d_ws, size_t ws_size,
                              hipStream_t stream)
{
  const float* hidden = (const float*)d_in[0];
  const float* gate_w = (const float*)d_in[1];
  const float* bias   = (const float*)d_in[2];
  const float* w_gate = (const float*)d_in[3];
  const float* w_up   = (const float*)d_in[4];
  const float* w_down = (const float*)d_in[5];
  float* out = (float*)d_out;

  char* ws = (char*)d_ws;
  size_t off = 0;
  #define WALLOC(bytes) (ws + off); off += (((size_t)(bytes)) + 255) & ~(size_t)255
  double* logits    = (double*)WALLOC((size_t)T_TOK*E_NUM*8);
  int*    topk_idx  = (int*)   WALLOC((size_t)T_TOK*TOPK*4);
  float*  topk_w    = (float*) WALLOC((size_t)T_TOK*TOPK*4);
  int*    counts    = (int*)   WALLOC(256);
  int*    cursor    = (int*)   WALLOC(256);
  int*    offsets   = (int*)   WALLOC(512);
  int*    blk_st    = (int*)   WALLOC(512);
  int*    token_l   = (int*)   WALLOC((size_t)S_ASN*4);
  float*  weight_l  = (float*) WALLOC((size_t)S_ASN*4);
  int*    pos_l     = (int*)   WALLOC((size_t)S_ASN*4);
  short*  h_all     = (short*) WALLOC((size_t)S_ASN*I_DIM*2);
  const size_t base_need = off;
  short*  hid_bf    = (short*) WALLOC((size_t)T_TOK*H_DIM*2);      /* 33.55 MB */
  short*  wg_bf     = (short*) WALLOC((size_t)E_NUM*I_DIM*H_DIM*2);/* 100.66 MB */
  short*  wu_bf     = (short*) WALLOC((size_t)E_NUM*I_DIM*H_DIM*2);
  short*  wd_bf     = (short*) WALLOC((size_t)E_NUM*H_DIM*I_DIM*2);
  const size_t fast_need = off;
  short*  y2        = (short*) WALLOC((size_t)S_ASN*H_DIM*2);      /* 268 MB  */
  const size_t fast2_need = off;
  #undef WALLOC
  /* half-mode y (S_ASN*512*2 = 134,217,728 B) aliases hid_bf+wg_bf
     (33,554,432 + 100,663,296 = 134,217,728 B exactly) — both dead once
     ffn1 completes. */
  short* y_all = hid_bf;

  const bool fast  = (ws_size >= fast_need);
  const bool fast2 = (ws_size >= fast2_need);
  if (ws_size < base_need) return;

  hipMemsetAsync(counts, 0, 512, stream);                 /* counts + cursor */

  gate_kernel   <<<T_TOK/64,  256, 0, stream>>>(hidden, gate_w, logits,
                                                fast ? hid_bf : (short*)0);
  route_kernel  <<<T_TOK/256, 256, 0, stream>>>(logits, bias, topk_idx, topk_w, counts);
  scan_kernel   <<<1, 64, 0, stream>>>(counts, offsets, blk_st);
  scatter_kernel<<<T_TOK/256, 256, 0, stream>>>(topk_idx, topk_w, offsets, cursor,
                                                token_l, weight_l, pos_l);
  if (fast){
    long n8w = (long)E_NUM*I_DIM*H_DIM/8;   /* 6,291,456 = 3072*256*8 exactly */
    cast_kernel<<<3072, 256, 0, stream>>>(w_gate, wg_bf, n8w);
    cast_kernel<<<3072, 256, 0, stream>>>(w_up,   wu_bf, n8w);
    cast_kernel<<<3072, 256, 0, stream>>>(w_down, wd_bf, n8w);
    dim3 g1(I_DIM/128, MAXBLK);  /* cb fast, row-block slow */
    ffn1_fast<<<g1, 512, 0, stream>>>(hid_bf, wg_bf, wu_bf, token_l, weight_l,
                                      offsets, blk_st, h_all);
    if (fast2){
      dim3 g2(8, MAXBLK);        /* single pass over all 1024 cols */
      ffn2y_fast<<<g2, 256, 0, stream>>>(h_all, wd_bf, offsets, blk_st,
                                         y2, 0, H_DIM);
      combine_kernel<<<T_TOK/2, 256, 0, stream>>>(y2, pos_l, out, 0, H_DIM, 0);
      combine_kernel<<<T_TOK/2, 256, 0, stream>>>(y2, pos_l, out, 1, H_DIM, 512);
    } else {
      dim3 g2(4, MAXBLK);
      for (int half = 0; half < 2; ++half){
        ffn2y_fast<<<g2, 256, 0, stream>>>(h_all, wd_bf, offsets, blk_st,
                                           y_all, half, 512);
        combine_kernel<<<T_TOK/2, 256, 0, stream>>>(y_all, pos_l, out,
                                                    half, 512, 0);
      }
    }
  } else {
    hipMemsetAsync(out, 0, (size_t)T_TOK*H_DIM*4, stream);
    dim3 g1(MAXBLK, I_DIM/128);
    ffn1_kernel<<<g1, 512, 0, stream>>>(hidden, w_gate, w_up, token_l, weight_l,
                                        offsets, blk_st, h_all);
    dim3 g2(MAXBLK, H_DIM/128);
    ffn2_kernel<<<g2, 512, 0, stream>>>(h_all, w_down, token_l, offsets, blk_st, out);
  }
}

// Round 11
// 1579.119 us; speedup vs baseline: 1.3007x; 1.0056x over previous
//
#include <hip/hip_runtime.h>
#include <hip/hip_bf16.h>
#include <math.h>

#define T_TOK 16384
#define H_DIM 1024
#define E_NUM 64
#define I_DIM 768
#define TOPK  8
#define NGRP  8
#define KGRP  4
#define S_ASN (T_TOK*TOPK)        /* 131072 assignments */
#define BM 128
#define BK 64
#define MAXBLK (S_ASN/BM + E_NUM) /* 1088: upper bound of sum(ceil(n_e/BM)) */

typedef __attribute__((ext_vector_type(4))) float f4v;
typedef __attribute__((ext_vector_type(8))) short s8v;
typedef __attribute__((ext_vector_type(4))) unsigned short u4sv;

#define GLDS16(g, l) __builtin_amdgcn_global_load_lds( \
    (const __attribute__((address_space(1))) void*)(g), \
    (__attribute__((address_space(3))) void*)(l), 16, 0, 0)

static __device__ __forceinline__ short f2bf(float f){
  union { float f; unsigned u; } a; a.f = f;
  unsigned u = a.u;
  unsigned r = (u + 0x7fffu + ((u >> 16) & 1u)) >> 16;  /* RNE */
  return (short)r;
}
static __device__ __forceinline__ float bf2f(unsigned short h){
  union { unsigned u; float f; } a; a.u = ((unsigned)h) << 16; return a.f;
}
static __device__ __forceinline__ s8v cvt8(f4v a, f4v b){
  s8v r;
  r[0]=f2bf(a[0]); r[1]=f2bf(a[1]); r[2]=f2bf(a[2]); r[3]=f2bf(a[3]);
  r[4]=f2bf(b[0]); r[5]=f2bf(b[1]); r[6]=f2bf(b[2]); r[7]=f2bf(b[3]);
  return r;
}

/* ---------------- fp32 -> bf16 bulk cast (non-temporal streaming) ---------- */
__launch_bounds__(256)
__global__ void cast_kernel(const float* __restrict__ src,
                            short* __restrict__ dst, long n8)
{
  long i = (long)blockIdx.x*blockDim.x + threadIdx.x;
  long stride = (long)gridDim.x*blockDim.x;
  for (; i < n8; i += stride){
    f4v a = __builtin_nontemporal_load((const f4v*)(src + i*8));
    f4v b = __builtin_nontemporal_load((const f4v*)(src + i*8 + 4));
    __builtin_nontemporal_store(cvt8(a, b), (s8v*)(dst + i*8));
  }
}

/* ---------------- gate logits + hidden bf16 side-output -------------------- */
__launch_bounds__(256)
__global__ void gate_kernel(const float* __restrict__ hidden,
                            const float* __restrict__ gate_w,
                            double* __restrict__ logits,
                            short*  __restrict__ hb)   /* may be null */
{
  __shared__ float sX[64][33];
  __shared__ float sW[64][33];
  const int tid  = threadIdx.x;
  const int t0   = blockIdx.x * 64;
  const int srow = tid >> 2;
  const int scol = (tid & 3) * 8;
  const int tx = tid & 15, ty = tid >> 4;
  double acc[4][4];
  #pragma unroll
  for (int i=0;i<4;i++)
    #pragma unroll
    for (int j=0;j<4;j++) acc[i][j]=0.0;

  for (int k0=0;k0<H_DIM;k0+=32){
    f4v a0 = *(const f4v*)&hidden[(size_t)(t0+srow)*H_DIM + k0 + scol];
    f4v a1 = *(const f4v*)&hidden[(size_t)(t0+srow)*H_DIM + k0 + scol + 4];
    f4v b0 = *(const f4v*)&gate_w[(size_t)srow*H_DIM + k0 + scol];
    f4v b1 = *(const f4v*)&gate_w[(size_t)srow*H_DIM + k0 + scol + 4];
    if (hb)  /* bf16 side-output: each element written exactly once */
      *(s8v*)&hb[(size_t)(t0+srow)*H_DIM + k0 + scol] = cvt8(a0, a1);
    __syncthreads();
    #pragma unroll
    for (int j=0;j<4;j++){
      sX[srow][scol+j]   = a0[j];  sX[srow][scol+4+j] = a1[j];
      sW[srow][scol+j]   = b0[j];  sW[srow][scol+4+j] = b1[j];
    }
    __syncthreads();
    #pragma unroll
    for (int kk=0;kk<32;kk++){
      float xv[4], wv[4];
      #pragma unroll
      for (int i=0;i<4;i++){ xv[i]=sX[ty*4+i][kk]; wv[i]=sW[tx*4+i][kk]; }
      #pragma unroll
      for (int i=0;i<4;i++)
        #pragma unroll
        for (int j=0;j<4;j++)
          acc[i][j] += (double)xv[i] * (double)wv[j];
    }
  }
  #pragma unroll
  for (int i=0;i<4;i++)
    #pragma unroll
    for (int j=0;j<4;j++)
      logits[(size_t)(t0+ty*4+i)*E_NUM + tx*4+j] = acc[i][j];
}

/* ---------------- routing: grouped top-k in fp64 --------------------------- */
__global__ void route_kernel(const double* __restrict__ logits,
                             const float*  __restrict__ bias,
                             int*   __restrict__ topk_idx,
                             float* __restrict__ topk_w,
                             int*   __restrict__ counts)
{
  const int t = blockIdx.x * blockDim.x + threadIdx.x;
  if (t >= T_TOK) return;
  const double* lg = logits + (size_t)t * E_NUM;
  double sc[E_NUM], sch[E_NUM];
  for (int e2=0;e2<E_NUM;e2++){
    double s = 1.0 / (1.0 + exp(-lg[e2]));
    sc[e2]  = s;
    sch[e2] = s + (double)bias[e2];
  }
  double gs[NGRP];
  for (int g=0;g<NGRP;g++){
    double m1=-1e300, m2=-1e300;
    for (int j=0;j<8;j++){
      double v = sch[g*8+j];
      if (v > m1){ m2 = m1; m1 = v; } else if (v > m2){ m2 = v; }
    }
    gs[g] = m1 + m2;
  }
  unsigned gsel = 0;
  for (int r=0;r<KGRP;r++){
    int best = 0; double bv = -1.0e308;
    for (int g=0;g<NGRP;g++)
      if (!((gsel>>g)&1u) && gs[g] > bv){ bv = gs[g]; best = g; }
    gsel |= 1u << best;
  }
  unsigned long long used = 0ULL;
  double wsum = 0.0;
  int sel[TOPK]; double w[TOPK];
  for (int r=0;r<TOPK;r++){
    int best = 0; double bv = -1.0e308;
    for (int e2=0;e2<E_NUM;e2++){
      if ((used>>e2)&1ULL) continue;
      if (!((gsel>>(e2>>3))&1u)) continue;
      if (sch[e2] > bv){ bv = sch[e2]; best = e2; }
    }
    used |= 1ULL << best;
    sel[r] = best;
    w[r]   = sc[best];
    wsum  += w[r];
  }
  double inv = 1.0 / (wsum + 1e-20);
  for (int r=0;r<TOPK;r++){
    topk_idx[(size_t)t*TOPK + r] = sel[r];
    topk_w  [(size_t)t*TOPK + r] = (float)(w[r]*inv);
    atomicAdd(&counts[sel[r]], 1);
  }
}

/* ---------------- prefix sums --------------------------------------------- */
__global__ void scan_kernel(const int* __restrict__ counts,
                            int* __restrict__ offsets,
                            int* __restrict__ blk_start)
{
  if (threadIdx.x == 0 && blockIdx.x == 0){
    int off = 0, blk = 0;
    for (int e=0;e<E_NUM;e++){
      offsets[e] = off; blk_start[e] = blk;
      off += counts[e];
      blk += (counts[e] + BM - 1) / BM;
    }
    offsets[E_NUM] = off; blk_start[E_NUM] = blk;
  }
}

/* ---------------- scatter token lists + inverse positions ------------------ */
__global__ void scatter_kernel(const int* __restrict__ topk_idx,
                               const float* __restrict__ topk_w,
                               const int* __restrict__ offsets,
                               int* __restrict__ cursor,
                               int* __restrict__ token_list,
                               float* __restrict__ weight_list,
                               int* __restrict__ pos_list)
{
  const int t = blockIdx.x*blockDim.x + threadIdx.x;
  if (t >= T_TOK) return;
  for (int r=0;r<TOPK;r++){
    int   e2 = topk_idx[(size_t)t*TOPK + r];
    float wv = topk_w [(size_t)t*TOPK + r];
    int p = atomicAdd(&cursor[e2], 1);
    token_list [offsets[e2] + p] = t;
    weight_list[offsets[e2] + p] = wv;
    pos_list[(size_t)t*TOPK + r] = offsets[e2] + p;
  }
}

/* ======================= FAST PATH (bf16 + global_load_lds) ================ */
/* LDS written LINEARLY by global_load_lds; XOR swizzle lives in the per-lane
   GLOBAL source address (inverse) and in the ds_read (forward):
   LDS slot (row, sl) holds global 16B-slot (sl ^ (row&7)).
   Grid axes: blockIdx.x = column-chunk (FAST: dispatch-adjacent blocks share
   one A-tile / one h_all row-block), blockIdx.y = row-block.                 */

/* ffn1: h = silu(X Wg^T) * (X Wu^T) * w.
   512 thr / 8 waves, BM=128, BN=128, BK=64. Wave-tile 64x32 (x2 for g,u). */
__launch_bounds__(512, 4)
__global__ void ffn1_fast(const short* __restrict__ hid_bf,
                          const short* __restrict__ wg_bf,
                          const short* __restrict__ wu_bf,
                          const int*   __restrict__ token_list,
                          const float* __restrict__ weight_list,
                          const int*   __restrict__ offsets,
                          const int*   __restrict__ blk_start,
                          short*       __restrict__ h_all)
{
  __shared__ short lsX[128*64];
  __shared__ short lsG[128*64];
  __shared__ short lsU[128*64];
  __shared__ float lsWt[128];

  const int bx = blockIdx.y;                 /* row-block index */
  if (bx >= blk_start[E_NUM]) return;
  int e = 0;
  while (blk_start[e+1] <= bx) ++e;
  const int rb   = bx - blk_start[e];
  const int cb   = blockIdx.x;               /* 0..5 : 128-col chunk of I */
  const int base = offsets[e];
  const int n_e  = offsets[e+1] - base;
  const int row0 = rb * BM;

  const int tid = threadIdx.x;
  const int lane = tid & 63, wid = tid >> 6;   /* 8 waves */
  const int wm = wid >> 2, wn = wid & 3;       /* 2 x 4 wave grid */
  const int l15 = lane & 15, l4 = lane >> 4;

  if (tid < BM) lsWt[tid] = ((row0+tid) < n_e) ? weight_list[base+row0+tid] : 0.f;

  const short* srcA[2];
  #pragma unroll
  for (int i=0;i<2;i++){
    int s_lin = i*512 + tid;
    int row = s_lin >> 3, sl = s_lin & 7;
    int asn = base + row0 + row; if (asn >= S_ASN) asn = S_ASN-1;
    int tok = token_list[asn];
    srcA[i] = hid_bf + (size_t)tok*H_DIM + ((sl ^ (row&7))<<3);
  }
  const short* srcG[2]; const short* srcU[2];
  #pragma unroll
  for (int i=0;i<2;i++){
    int s_lin = i*512 + tid;
    int row = s_lin >> 3, sl = s_lin & 7;
    size_t wrow = ((size_t)e*I_DIM + cb*128 + row)*H_DIM + ((sl ^ (row&7))<<3);
    srcG[i] = wg_bf + wrow;
    srcU[i] = wu_bf + wrow;
  }
  short* dstA0 = lsX + wid*512;
  short* dstG0 = lsG + wid*512;
  short* dstU0 = lsU + wid*512;

  f4v accg[4][2], accu[4][2];
  #pragma unroll
  for (int m=0;m<4;m++)
    #pragma unroll
    for (int n=0;n<2;n++){
      accg[m][n]=(f4v){0.f,0.f,0.f,0.f};
      accu[m][n]=(f4v){0.f,0.f,0.f,0.f};
    }

  for (int k0=0; k0<H_DIM; k0+=BK){
    __syncthreads();
    #pragma unroll
    for (int i=0;i<2;i++) GLDS16(srcA[i]+k0, dstA0 + i*4096);
    #pragma unroll
    for (int i=0;i<2;i++) GLDS16(srcG[i]+k0, dstG0 + i*4096);
    #pragma unroll
    for (int i=0;i<2;i++) GLDS16(srcU[i]+k0, dstU0 + i*4096);
    __syncthreads();
    #pragma unroll
    for (int kk=0;kk<2;kk++){
      s8v af[4], bg[2], bu[2];
      #pragma unroll
      for (int m=0;m<4;m++){
        int r = wm*64 + m*16 + l15;
        int s = (kk*4 + l4) ^ (r & 7);
        af[m] = *(const s8v*)&lsX[r*64 + (s<<3)];
      }
      #pragma unroll
      for (int n=0;n<2;n++){
        int r = wn*32 + n*16 + l15;
        int s = (kk*4 + l4) ^ (r & 7);
        bg[n] = *(const s8v*)&lsG[r*64 + (s<<3)];
        bu[n] = *(const s8v*)&lsU[r*64 + (s<<3)];
      }
      #pragma unroll
      for (int m=0;m<4;m++)
        #pragma unroll
        for (int n=0;n<2;n++){
          accg[m][n] = __builtin_amdgcn_mfma_f32_16x16x32_bf16(af[m], bg[n], accg[m][n], 0,0,0);
          accu[m][n] = __builtin_amdgcn_mfma_f32_16x16x32_bf16(af[m], bu[n], accu[m][n], 0,0,0);
        }
    }
  }
  #pragma unroll
  for (int m=0;m<4;m++){
    #pragma unroll
    for (int i=0;i<4;i++){
      int r = wm*64 + m*16 + l4*4 + i;
      if (row0 + r < n_e){
        float wgt = lsWt[r];
        size_t hb = (size_t)(base+row0+r)*I_DIM + (size_t)cb*128;
        #pragma unroll
        for (int n=0;n<2;n++){
          int c = wn*32 + n*16 + l15;
          float g = accg[m][n][i], u = accu[m][n][i];
          float s = g / (1.f + __expf(-g));
          h_all[hb + c] = f2bf(s * u * wgt);   /* cached store: L2 aggregates */
        }
      }
    }
  }
}

/* ffn2y: y[asn, cols] = h_all @ Wd^T  (dense bf16 writes, NO atomics).
   Round-4 verified GEMM config: 256 thr / 4 waves (2x2), BM=128, BN=128,
   BK=64, wave-tile 64x64, acc[4][4].  blockIdx.x = cby (fast), .y = rowblk.
   Single-pass mode: cb0=0, gridDim.x=8, ystride=1024.
   Half mode:        cb0 in {0,1}, gridDim.x=4, ystride=512.                 */
__launch_bounds__(256, 3)
__global__ void ffn2y_fast(const short* __restrict__ h_all,
                           const short* __restrict__ wd_bf,
                           const int*   __restrict__ offsets,
                           const int*   __restrict__ blk_start,
                           short*       __restrict__ y,
                           int          cb0,
                           int          ystride)
{
  __shared__ short lsA[128*64];
  __shared__ short lsB[128*64];

  const int bx = blockIdx.y;                 /* row-block index */
  if (bx >= blk_start[E_NUM]) return;
  int e = 0;
  while (blk_start[e+1] <= bx) ++e;
  const int rb   = bx - blk_start[e];
  const int cby  = blockIdx.x;               /* col-chunk within this launch */
  const int cbg  = cb0*4 + cby;              /* global 128-col chunk of H */
  const int base = offsets[e];
  const int n_e  = offsets[e+1] - base;
  const int row0 = rb * BM;

  const int tid = threadIdx.x;
  const int lane = tid & 63, wid = tid >> 6;
  const int wm = wid >> 1, wn = wid & 1;     /* 2 x 2 wave grid */
  const int l15 = lane & 15, l4 = lane >> 4;

  const short* srcA[4]; const short* srcB[4];
  #pragma unroll
  for (int i=0;i<4;i++){
    int s_lin = i*256 + tid;
    int row = s_lin >> 3, sl = s_lin & 7;
    int arow = base + row0 + row; if (arow >= S_ASN) arow = S_ASN-1;
    srcA[i] = h_all + (size_t)arow*I_DIM + ((sl ^ (row&7))<<3);
    srcB[i] = wd_bf + ((size_t)e*H_DIM + cbg*128 + row)*I_DIM + ((sl ^ (row&7))<<3);
  }
  short* dstA0 = lsA + wid*512;
  short* dstB0 = lsB + wid*512;

  f4v acc[4][4];
  #pragma unroll
  for (int m=0;m<4;m++)
    #pragma unroll
    for (int n=0;n<4;n++) acc[m][n]=(f4v){0.f,0.f,0.f,0.f};

  for (int k0=0; k0<I_DIM; k0+=BK){
    __syncthreads();
    #pragma unroll
    for (int i=0;i<4;i++) GLDS16(srcA[i]+k0, dstA0 + i*2048);
    #pragma unroll
    for (int i=0;i<4;i++) GLDS16(srcB[i]+k0, dstB0 + i*2048);
    __syncthreads();
    #pragma unroll
    for (int kk=0;kk<2;kk++){
      s8v af[4], bf[4];
      #pragma unroll
      for (int m=0;m<4;m++){
        int r = wm*64 + m*16 + l15;
        int s = (kk*4 + l4) ^ (r & 7);
        af[m] = *(const s8v*)&lsA[r*64 + (s<<3)];
      }
      #pragma unroll
      for (int n=0;n<4;n++){
        int r = wn*64 + n*16 + l15;
        int s = (kk*4 + l4) ^ (r & 7);
        bf[n] = *(const s8v*)&lsB[r*64 + (s<<3)];
      }
      #pragma unroll
      for (int m=0;m<4;m++)
        #pragma unroll
        for (int n=0;n<4;n++)
          acc[m][n] = __builtin_amdgcn_mfma_f32_16x16x32_bf16(af[m], bf[n], acc[m][n], 0,0,0);
    }
  }
  #pragma unroll
  for (int m=0;m<4;m++){
    #pragma unroll
    for (int i=0;i<4;i++){
      int r = wm*64 + m*16 + l4*4 + i;
      if (row0 + r < n_e){
        size_t yb = (size_t)(base+row0+r)*ystride + (size_t)cby*128;
        #pragma unroll
        for (int n=0;n<4;n++){
          int c = wn*64 + n*16 + l15;
          y[yb + c] = f2bf(acc[m][n][i]);
        }
      }
    }
  }
}

/* combine_full: out[t, :] = sum_r y[pos[t,r], :]  (one block per token,
   256 thr x 4 cols = 1024 cols; y rows are read exactly once -> nt loads) */
__launch_bounds__(256)
__global__ void combine_full(const short* __restrict__ y,
                             const int*   __restrict__ pos,
                             float*       __restrict__ out)
{
  const int t = blockIdx.x;
  const int c = threadIdx.x * 4;
  const int* pp = pos + (size_t)t*TOPK;
  float s0=0.f, s1=0.f, s2=0.f, s3=0.f;
  #pragma unroll
  for (int r=0;r<TOPK;r++){
    int row = pp[r];
    u4sv v = __builtin_nontemporal_load((const u4sv*)&y[(size_t)row*H_DIM + c]);
    s0 += bf2f(v[0]); s1 += bf2f(v[1]); s2 += bf2f(v[2]); s3 += bf2f(v[3]);
  }
  f4v o = {s0,s1,s2,s3};
  *(f4v*)&out[(size_t)t*H_DIM + c] = o;
}

/* combine (half mode): out[t, cb0*512 + c] = sum_r y[pos[t,r], c] */
__launch_bounds__(256)
__global__ void combine_kernel(const short* __restrict__ y,
                               const int*   __restrict__ pos,
                               float*       __restrict__ out,
                               int cb0)
{
  const int tid = threadIdx.x;
  const int t = blockIdx.x*2 + (tid >> 7);
  const int c = (tid & 127) * 4;
  const int* pp = pos + (size_t)t*TOPK;
  float s0=0.f, s1=0.f, s2=0.f, s3=0.f;
  #pragma unroll
  for (int r=0;r<TOPK;r++){
    int row = pp[r];
    u4sv v = *(const u4sv*)&y[(size_t)row*512 + c];
    s0 += bf2f(v[0]); s1 += bf2f(v[1]); s2 += bf2f(v[2]); s3 += bf2f(v[3]);
  }
  f4v o = {s0,s1,s2,s3};
  *(f4v*)&out[(size_t)t*H_DIM + (size_t)cb0*512 + c] = o;
}

/* ======================= SLOW FALLBACK (round-1, fp32 reg-staged) ========== */
__launch_bounds__(512, 2)
__global__ void ffn1_kernel(const float* __restrict__ hidden,
                            const float* __restrict__ w_gate,
                            const float* __restrict__ w_up,
                            const int*   __restrict__ token_list,
                            const float* __restrict__ weight_list,
                            const int*   __restrict__ offsets,
                            const int*   __restrict__ blk_start,
                            short*       __restrict__ h_all)
{
  __shared__ short lsX[BM*64];
  __shared__ short lsG[BM*64];
  __shared__ short lsU[BM*64];
  __shared__ float lsWt[BM];

  const int bx = blockIdx.x;
  if (bx >= blk_start[E_NUM]) return;
  int e = 0;
  while (blk_start[e+1] <= bx) ++e;
  const int rb   = bx - blk_start[e];
  const int cb   = blockIdx.y;
  const int base = offsets[e];
  const int n_e  = offsets[e+1] - base;
  const int row0 = rb * BM;

  const int tid   = threadIdx.x;
  const int srow  = tid >> 2;
  const int scol  = (tid & 3) << 4;
  const int slot0 = (tid & 3) << 1;
  const int wsl0  = srow*64 + (((slot0  ) ^ (srow & 7)) << 3);
  const int wsl1  = srow*64 + (((slot0+1) ^ (srow & 7)) << 3);

  const bool tvalid = (row0 + srow) < n_e;
  int tok = 0;
  if (tvalid) tok = token_list[base + row0 + srow];
  const float* xsrc = hidden + (size_t)tok * H_DIM + scol;
  const size_t woff = (size_t)e * I_DIM * H_DIM + (size_t)(cb*128 + srow) * H_DIM + scol;
  const float* gsrc = w_gate + woff;
  const float* usrc = w_up   + woff;

  const int lane = tid & 63, wid = tid >> 6;
  const int wm = wid >> 2, wn = wid & 3;
  const int l15 = lane & 15, l4 = lane >> 4;

  f4v accg[4][2], accu[4][2];
  #pragma unroll
  for (int m=0;m<4;m++)
    #pragma unroll
    for (int n=0;n<2;n++){
      accg[m][n]=(f4v){0.f,0.f,0.f,0.f};
      accu[m][n]=(f4v){0.f,0.f,0.f,0.f};
    }

  for (int k0=0; k0<H_DIM; k0+=BK){
    f4v x0,x1,x2,x3;
    if (tvalid){
      x0 = *(const f4v*)(xsrc+k0);   x1 = *(const f4v*)(xsrc+k0+4);
      x2 = *(const f4v*)(xsrc+k0+8); x3 = *(const f4v*)(xsrc+k0+12);
    } else {
      x0=x1=x2=x3=(f4v){0.f,0.f,0.f,0.f};
    }
    f4v g0 = *(const f4v*)(gsrc+k0),   g1 = *(const f4v*)(gsrc+k0+4);
    f4v g2 = *(const f4v*)(gsrc+k0+8), g3 = *(const f4v*)(gsrc+k0+12);
    f4v u0 = *(const f4v*)(usrc+k0),   u1 = *(const f4v*)(usrc+k0+4);
    f4v u2 = *(const f4v*)(usrc+k0+8), u3 = *(const f4v*)(usrc+k0+12);
    __syncthreads();
    *(s8v*)&lsX[wsl0] = cvt8(x0,x1);  *(s8v*)&lsX[wsl1] = cvt8(x2,x3);
    *(s8v*)&lsG[wsl0] = cvt8(g0,g1);  *(s8v*)&lsG[wsl1] = cvt8(g2,g3);
    *(s8v*)&lsU[wsl0] = cvt8(u0,u1);  *(s8v*)&lsU[wsl1] = cvt8(u2,u3);
    __syncthreads();
    #pragma unroll
    for (int kk=0;kk<2;kk++){
      s8v af[4], bg[2], bu[2];
      #pragma unroll
      for (int m=0;m<4;m++){
        int r = wm*64 + m*16 + l15;
        int s = (kk*4 + l4) ^ (r & 7);
        af[m] = *(const s8v*)&lsX[r*64 + (s<<3)];
      }
      #pragma unroll
      for (int n=0;n<2;n++){
        int r = wn*32 + n*16 + l15;
        int s = (kk*4 + l4) ^ (r & 7);
        bg[n] = *(const s8v*)&lsG[r*64 + (s<<3)];
        bu[n] = *(const s8v*)&lsU[r*64 + (s<<3)];
      }
      #pragma unroll
      for (int m=0;m<4;m++)
        #pragma unroll
        for (int n=0;n<2;n++){
          accg[m][n] = __builtin_amdgcn_mfma_f32_16x16x32_bf16(af[m], bg[n], accg[m][n], 0,0,0);
          accu[m][n] = __builtin_amdgcn_mfma_f32_16x16x32_bf16(af[m], bu[n], accu[m][n], 0,0,0);
        }
    }
  }
  if (tid < BM) lsWt[tid] = ((row0+tid) < n_e) ? weight_list[base+row0+tid] : 0.f;
  __syncthreads();
  #pragma unroll
  for (int m=0;m<4;m++){
    #pragma unroll
    for (int i=0;i<4;i++){
      int r = wm*64 + m*16 + l4*4 + i;
      if (row0 + r < n_e){
        float wgt = lsWt[r];
        size_t hb = (size_t)(base+row0+r)*I_DIM + (size_t)cb*128;
        #pragma unroll
        for (int n=0;n<2;n++){
          int c = wn*32 + n*16 + l15;
          float g = accg[m][n][i], u = accu[m][n][i];
          float s = g / (1.f + __expf(-g));
          h_all[hb + c] = f2bf(s * u * wgt);
        }
      }
    }
  }
}

__launch_bounds__(512, 2)
__global__ void ffn2_kernel(const short* __restrict__ h_all,
                            const float* __restrict__ w_down,
                            const int*   __restrict__ token_list,
                            const int*   __restrict__ offsets,
                            const int*   __restrict__ blk_start,
                            float*       __restrict__ out)
{
  __shared__ short lsA[BM*64];
  __shared__ short lsB[BM*64];
  __shared__ int   lsT[BM];

  const int bx = blockIdx.x;
  if (bx >= blk_start[E_NUM]) return;
  int e = 0;
  while (blk_start[e+1] <= bx) ++e;
  const int rb   = bx - blk_start[e];
  const int cb   = blockIdx.y;
  const int base = offsets[e];
  const int n_e  = offsets[e+1] - base;
  const int row0 = rb * BM;

  const int tid   = threadIdx.x;
  const int srow  = tid >> 2;
  const int slot0 = (tid & 3) << 1;
  const int wsl0  = srow*64 + (((slot0  ) ^ (srow & 7)) << 3);
  const int wsl1  = srow*64 + (((slot0+1) ^ (srow & 7)) << 3);

  int arow = base + row0 + srow;
  if (arow >= S_ASN) arow = S_ASN - 1;
  const short* asrc = h_all + (size_t)arow*I_DIM + ((tid&3)<<4);
  const float* bsrc = w_down + (size_t)e*H_DIM*I_DIM
                    + (size_t)(cb*128 + srow)*I_DIM + ((tid&3)<<4);

  const int lane = tid & 63, wid = tid >> 6;
  const int wm = wid >> 2, wn = wid & 3;
  const int l15 = lane & 15, l4 = lane >> 4;

  f4v acc[4][2];
  #pragma unroll
  for (int m=0;m<4;m++)
    #pragma unroll
    for (int n=0;n<2;n++) acc[m][n]=(f4v){0.f,0.f,0.f,0.f};

  for (int k0=0; k0<I_DIM; k0+=BK){
    s8v alo = *(const s8v*)(asrc + k0);
    s8v ahi = *(const s8v*)(asrc + k0 + 8);
    f4v b0 = *(const f4v*)(bsrc+k0),   b1 = *(const f4v*)(bsrc+k0+4);
    f4v b2 = *(const f4v*)(bsrc+k0+8), b3 = *(const f4v*)(bsrc+k0+12);
    __syncthreads();
    *(s8v*)&lsA[wsl0] = alo;          *(s8v*)&lsA[wsl1] = ahi;
    *(s8v*)&lsB[wsl0] = cvt8(b0,b1);  *(s8v*)&lsB[wsl1] = cvt8(b2,b3);
    __syncthreads();
    #pragma unroll
    for (int kk=0;kk<2;kk++){
      s8v af[4], bf[2];
      #pragma unroll
      for (int m=0;m<4;m++){
        int r = wm*64 + m*16 + l15;
        int s = (kk*4 + l4) ^ (r & 7);
        af[m] = *(const s8v*)&lsA[r*64 + (s<<3)];
      }
      #pragma unroll
      for (int n=0;n<2;n++){
        int r = wn*32 + n*16 + l15;
        int s = (kk*4 + l4) ^ (r & 7);
        bf[n] = *(const s8v*)&lsB[r*64 + (s<<3)];
      }
      #pragma unroll
      for (int m=0;m<4;m++)
        #pragma unroll
        for (int n=0;n<2;n++)
          acc[m][n] = __builtin_amdgcn_mfma_f32_16x16x32_bf16(af[m], bf[n], acc[m][n], 0,0,0);
    }
  }
  if (tid < BM) lsT[tid] = ((row0+tid) < n_e) ? token_list[base+row0+tid] : -1;
  __syncthreads();
  #pragma unroll
  for (int m=0;m<4;m++){
    #pragma unroll
    for (int i=0;i<4;i++){
      int r = wm*64 + m*16 + l4*4 + i;
      int tk = lsT[r];
      if (tk >= 0){
        #pragma unroll
        for (int n=0;n<2;n++){
          int c = cb*128 + wn*32 + n*16 + l15;
          atomicAdd(&out[(size_t)tk*H_DIM + c], acc[m][n][i]);
        }
      }
    }
  }
}

/* ---------------- launch --------------------------------------------------- */
extern "C" void kernel_launch(void* const* d_in, const int* in_sizes, int n_in,
                              void* d_out, int out_size, void* d_ws, size_t ws_size,
                              hipStream_t stream)
{
  const float* hidden = (const float*)d_in[0];
  const float* gate_w = (const float*)d_in[1];
  const float* bias   = (const float*)d_in[2];
  const float* w_gate = (const float*)d_in[3];
  const float* w_up   = (const float*)d_in[4];
  const float* w_down = (const float*)d_in[5];
  float* out = (float*)d_out;

  char* ws = (char*)d_ws;
  size_t off = 0;
  #define WALLOC(bytes) (ws + off); off += (((size_t)(bytes)) + 255) & ~(size_t)255
  double* logits    = (double*)WALLOC((size_t)T_TOK*E_NUM*8);
  int*    topk_idx  = (int*)   WALLOC((size_t)T_TOK*TOPK*4);
  float*  topk_w    = (float*) WALLOC((size_t)T_TOK*TOPK*4);
  int*    counts    = (int*)   WALLOC(256);
  int*    cursor    = (int*)   WALLOC(256);
  int*    offsets   = (int*)   WALLOC(512);
  int*    blk_st    = (int*)   WALLOC(512);
  int*    token_l   = (int*)   WALLOC((size_t)S_ASN*4);
  float*  weight_l  = (float*) WALLOC((size_t)S_ASN*4);
  int*    pos_l     = (int*)   WALLOC((size_t)S_ASN*4);
  short*  h_all     = (short*) WALLOC((size_t)S_ASN*I_DIM*2);
  const size_t base_need = off;
  short*  hid_bf    = (short*) WALLOC((size_t)T_TOK*H_DIM*2);      /* 33.55 MB */
  short*  wg_bf     = (short*) WALLOC((size_t)E_NUM*I_DIM*H_DIM*2);/* 100.66 MB */
  short*  wu_bf     = (short*) WALLOC((size_t)E_NUM*I_DIM*H_DIM*2);
  short*  wd_bf     = (short*) WALLOC((size_t)E_NUM*H_DIM*I_DIM*2);
  const size_t fast_need = off;
  short*  y2        = (short*) WALLOC((size_t)S_ASN*H_DIM*2);      /* 268 MB  */
  const size_t fast2_need = off;
  #undef WALLOC
  /* half-mode y (S_ASN*512*2 = 134,217,728 B) aliases hid_bf+wg_bf
     (33,554,432 + 100,663,296 = 134,217,728 B exactly) — both dead once
     ffn1 completes. */
  short* y_all = hid_bf;

  const bool fast  = (ws_size >= fast_need);
  const bool fast2 = (ws_size >= fast2_need);
  if (ws_size < base_need) return;

  hipMemsetAsync(counts, 0, 512, stream);                 /* counts + cursor */

  gate_kernel   <<<T_TOK/64,  256, 0, stream>>>(hidden, gate_w, logits,
                                                fast ? hid_bf : (short*)0);
  route_kernel  <<<T_TOK/256, 256, 0, stream>>>(logits, bias, topk_idx, topk_w, counts);
  scan_kernel   <<<1, 64, 0, stream>>>(counts, offsets, blk_st);
  scatter_kernel<<<T_TOK/256, 256, 0, stream>>>(topk_idx, topk_w, offsets, cursor,
                                                token_l, weight_l, pos_l);
  if (fast){
    long n8w = (long)E_NUM*I_DIM*H_DIM/8;   /* 6,291,456 = 3072*256*8 exactly */
    cast_kernel<<<3072, 256, 0, stream>>>(w_gate, wg_bf, n8w);
    cast_kernel<<<3072, 256, 0, stream>>>(w_up,   wu_bf, n8w);
    cast_kernel<<<3072, 256, 0, stream>>>(w_down, wd_bf, n8w);
    dim3 g1(I_DIM/128, MAXBLK);  /* cb fast, row-block slow */
    ffn1_fast<<<g1, 512, 0, stream>>>(hid_bf, wg_bf, wu_bf, token_l, weight_l,
                                      offsets, blk_st, h_all);
    if (fast2){
      dim3 g2(8, MAXBLK);        /* single pass over all 1024 cols */
      ffn2y_fast<<<g2, 256, 0, stream>>>(h_all, wd_bf, offsets, blk_st,
                                         y2, 0, H_DIM);
      combine_full<<<T_TOK, 256, 0, stream>>>(y2, pos_l, out);
    } else {
      dim3 g2(4, MAXBLK);
      for (int half = 0; half < 2; ++half){
        ffn2y_fast<<<g2, 256, 0, stream>>>(h_all, wd_bf, offsets, blk_st,
                                           y_all, half, 512);
        combine_kernel<<<T_TOK/2, 256, 0, stream>>>(y_all, pos_l, out, half);
      }
    }
  } else {
    hipMemsetAsync(out, 0, (size_t)T_TOK*H_DIM*4, stream);
    dim3 g1(MAXBLK, I_DIM/128);
    ffn1_kernel<<<g1, 512, 0, stream>>>(hidden, w_gate, w_up, token_l, weight_l,
                                        offsets, blk_st, h_all);
    dim3 g2(MAXBLK, H_DIM/128);
    ffn2_kernel<<<g2, 512, 0, stream>>>(h_all, w_down, token_l, offsets, blk_st, out);
  }
}